// Round 14
// baseline (7746.014 us; speedup 1.0000x reference)
//
#include <hip/hip_runtime.h>
#include <hip/hip_bf16.h>
#include <math.h>

#define N_NODES 4096
#define WPN 32
#define HID 1024
#define VOCAB 30000
#define NCLASS 4
#define NLEAVES 1024

typedef unsigned int u32;
typedef unsigned short u16;

__device__ __forceinline__ float sigmf(float x){ return 1.f/(1.f+expf(-x)); }

// ---------------------------------------------------------------------------
// Level schedule: depth[i] via iterative relaxation in LDS, then counting sort.
// Also zeroes node_h row 0 (root parent).
// ---------------------------------------------------------------------------
__global__ __launch_bounds__(1024) void k_levels(const int* __restrict__ parent,
                                                 int* __restrict__ meta,
                                                 int* __restrict__ lstart,
                                                 int* __restrict__ order,
                                                 float* __restrict__ node_h){
  __shared__ int dep[N_NODES];
  __shared__ int dpt[N_NODES];
  __shared__ int cnt[N_NODES];
  __shared__ int changed, maxd;
  const int t = threadIdx.x;
  for(int i=t;i<N_NODES;i+=1024){ dep[i]=parent[i]-1; dpt[i]=0; cnt[i]=0; }
  if(t==0){ maxd=0; }
  node_h[t]=0.f;  // 1024 threads == HID: zero root-parent row
  __syncthreads();
  while(true){
    if(t==0) changed=0;
    __syncthreads();
    bool ch=false;
    for(int i=t;i<N_NODES;i+=1024){
      int d = (dep[i]<0)? 0 : (dpt[dep[i]]+1);
      if(d>dpt[i]){ dpt[i]=d; ch=true; }
    }
    if(ch) changed=1;
    __syncthreads();
    if(!changed) break;
    __syncthreads();
  }
  __syncthreads();
  for(int i=t;i<N_NODES;i+=1024){ atomicAdd(&cnt[dpt[i]],1); atomicMax(&maxd,dpt[i]); }
  __syncthreads();
  // inclusive scan of cnt -> sc (reuse dep)
  int* sc = dep;
  for(int i=t;i<N_NODES;i+=1024) sc[i]=cnt[i];
  __syncthreads();
  for(int off=1; off<N_NODES; off<<=1){
    int v[4];
    #pragma unroll
    for(int u=0;u<4;u++){ int i=t+u*1024; v[u] = (i>=off)? sc[i-off] : 0; }
    __syncthreads();
    #pragma unroll
    for(int u=0;u<4;u++){ int i=t+u*1024; sc[i]+=v[u]; }
    __syncthreads();
  }
  for(int i=t;i<N_NODES;i+=1024) lstart[i+1]=sc[i];
  if(t==0){ lstart[0]=0; meta[0]=maxd+1; }
  // exclusive starts into cnt for scatter
  for(int i=t;i<N_NODES;i+=1024) cnt[i]=sc[i]-cnt[i];
  __syncthreads();
  for(int i=t;i<N_NODES;i+=1024){
    int pos = atomicAdd(&cnt[dpt[i]],1);
    order[pos]=i;
  }
}

// ---------------------------------------------------------------------------
// E [HID][VOCAB] f32  ->  ET [VOCAB][HID] f32  (tiled transpose)
// ---------------------------------------------------------------------------
__global__ __launch_bounds__(256) void k_transpose(const float* __restrict__ E,
                                                   float* __restrict__ ET){
  __shared__ float tile[32][33];
  const int v0 = blockIdx.x*32, h0 = blockIdx.y*32;
  const int tx = threadIdx.x%32, ty = threadIdx.x/32;   // ty 0..7
  #pragma unroll
  for(int i=0;i<4;i++){
    int h = h0+ty+8*i, v = v0+tx;
    tile[ty+8*i][tx] = (v<VOCAB)? E[(size_t)h*VOCAB + v] : 0.f;
  }
  __syncthreads();
  #pragma unroll
  for(int i=0;i<4;i++){
    int v = v0+ty+8*i, h = h0+tx;
    if(v<VOCAB) ET[(size_t)v*HID + h] = tile[tx][ty+8*i];
  }
}

// ---------------------------------------------------------------------------
// xe[n,h] = sum_l w[n,l] * ET[idx[n,l], h]   (one block per node, coalesced)
// ---------------------------------------------------------------------------
__global__ __launch_bounds__(256) void k_xe(const float* __restrict__ ET,
                                            const float* __restrict__ xw,
                                            const int* __restrict__ xi,
                                            float* __restrict__ xe){
  const int n = blockIdx.x;
  __shared__ float w[WPN]; __shared__ int id[WPN];
  const int t = threadIdx.x;
  if(t<WPN){ w[t]=xw[n*WPN+t]; id[t]=xi[n*WPN+t]; }
  __syncthreads();
  const int h0 = t*4;
  float a0=0,a1=0,a2=0,a3=0;
  for(int l=0;l<WPN;l++){
    const float4 e = *(const float4*)(ET + (size_t)id[l]*HID + h0);
    const float wl = w[l];
    a0 += wl*e.x; a1 += wl*e.y; a2 += wl*e.z; a3 += wl*e.w;
  }
  *(float4*)(xe + (size_t)n*HID + h0) = make_float4(a0,a1,a2,a3);
}

// Fallback when ws too small for fp32 ET: direct strided gather from E.
__global__ __launch_bounds__(256) void k_xe_noET(const float* __restrict__ E,
                                                 const float* __restrict__ xw,
                                                 const int* __restrict__ xi,
                                                 float* __restrict__ xe){
  const int n = blockIdx.x;
  __shared__ float w[WPN]; __shared__ int id[WPN];
  const int t = threadIdx.x;
  if(t<WPN){ w[t]=xw[n*WPN+t]; id[t]=xi[n*WPN+t]; }
  __syncthreads();
  const int h0 = t*4;
  float acc[4]={0,0,0,0};
  for(int l=0;l<WPN;l++){
    const float wl=w[l]; const int ix=id[l];
    #pragma unroll
    for(int j=0;j<4;j++) acc[j] += wl*E[(size_t)(h0+j)*VOCAB + ix];
  }
  *(float4*)(xe + (size_t)n*HID + h0) = make_float4(acc[0],acc[1],acc[2],acc[3]);
}

// ---------------------------------------------------------------------------
// Input-side projections: out_g[n,o] = b_g[o] + sum_k xe[n,k]*W_g[o,k]
// 64x64 tile, BK=32, k-major LDS, 4x4 micro-tile.
// ---------------------------------------------------------------------------
__global__ __launch_bounds__(256) void k_gemm_in(const float* __restrict__ xe,
  const float* __restrict__ W0,const float* __restrict__ W1,const float* __restrict__ W2,
  const float* __restrict__ b0,const float* __restrict__ b1,const float* __restrict__ b2,
  float* __restrict__ o0p,float* __restrict__ o1p,float* __restrict__ o2p){
  __shared__ float A[32*68];
  __shared__ float B[32*68];
  const int g=blockIdx.z;
  const float* W  = (g==0)?W0:((g==1)?W1:W2);
  const float* bi = (g==0)?b0:((g==1)?b1:b2);
  float* out      = (g==0)?o0p:((g==1)?o1p:o2p);
  const int n0=blockIdx.x<<6, q0=blockIdx.y<<6;
  const int t=threadIdx.x, tx=t&15, ty=t>>4;
  float acc[4][4]={};
  for(int k0=0;k0<HID;k0+=32){
    #pragma unroll
    for(int m=0;m<2;m++){
      int idx=t+(m<<8); int r=idx>>3; int c4=(idx&7)<<2;
      float4 v=*(const float4*)(xe+(size_t)(n0+r)*HID+k0+c4);
      A[(c4+0)*68+r]=v.x; A[(c4+1)*68+r]=v.y; A[(c4+2)*68+r]=v.z; A[(c4+3)*68+r]=v.w;
      float4 u=*(const float4*)(W+(size_t)(q0+r)*HID+k0+c4);
      B[(c4+0)*68+r]=u.x; B[(c4+1)*68+r]=u.y; B[(c4+2)*68+r]=u.z; B[(c4+3)*68+r]=u.w;
    }
    __syncthreads();
    #pragma unroll 8
    for(int k=0;k<32;k++){
      const float4 a=*(const float4*)&A[k*68+(ty<<2)];
      const float4 b=*(const float4*)&B[k*68+(tx<<2)];
      acc[0][0]+=a.x*b.x; acc[0][1]+=a.x*b.y; acc[0][2]+=a.x*b.z; acc[0][3]+=a.x*b.w;
      acc[1][0]+=a.y*b.x; acc[1][1]+=a.y*b.y; acc[1][2]+=a.y*b.z; acc[1][3]+=a.y*b.w;
      acc[2][0]+=a.z*b.x; acc[2][1]+=a.z*b.y; acc[2][2]+=a.z*b.z; acc[2][3]+=a.z*b.w;
      acc[3][0]+=a.w*b.x; acc[3][1]+=a.w*b.y; acc[3][2]+=a.w*b.z; acc[3][3]+=a.w*b.w;
    }
    __syncthreads();
  }
  const float4 bb=*(const float4*)(bi+q0+(tx<<2));
  #pragma unroll
  for(int i=0;i<4;i++){
    const int n=n0+(ty<<2)+i;
    float4 r4 = make_float4(acc[i][0]+bb.x, acc[i][1]+bb.y, acc[i][2]+bb.z, acc[i][3]+bb.w);
    *(float4*)(out+(size_t)n*HID+q0+(tx<<2)) = r4;
  }
}

// ---------------------------------------------------------------------------
// Persistent level-synchronous recurrence, v14 "tier fix":
//  Allocator ledger: (512,2)->124 VGPR no-spill (r9,r10); (256,4)/(512,4)/
//  (1024,4)->64 VGPR + scratch spill of pinned payload (r11,r12,r13: FETCH
//  483MB/7.3GB/557MB). Law: min-waves>=4 makes the backend over-shoot to the
//  64-VGPR tier and spill. v14 = round-13 structure with the ONE change
//  (1024,4)->(1024,2): 256 blocks x 1024 threads (16 waves = 4 waves/SIMD
//  from block size alone, 1 block/CU guaranteed -> no deadlock), min=2 puts
//  the allocator in the 256-cap tier where it historically picks ~124.
//  Everything else identical to round 13: 8 groups x 32 blocks (81MB
//  broadcast regime), phase A 4 rows/wave bf16-packed (32 pinned u32),
//  phase C 2 rows/wave with fp32 Uh in 128KB LDS, 2-deep bb prefetch.
// ---------------------------------------------------------------------------
#define REC_GRID 256
#define GRPSH 4
#define GRP   (1<<GRPSH)            // 16 blocks per barrier-group
#define NGRP  (REC_GRID>>GRPSH)     // 16 groups

__device__ __forceinline__ void gbar(u32* bar){
  __syncthreads();
  if(threadIdx.x==0){
    __threadfence();
    u32* gen  = bar;
    u32* gcnt = bar + 16 + ((blockIdx.x>>GRPSH)<<4);
    u32* root = bar + 16 + (NGRP<<4);
    u32 g = __hip_atomic_load(gen, __ATOMIC_RELAXED, __HIP_MEMORY_SCOPE_AGENT);
    u32 a = __hip_atomic_fetch_add(gcnt, 1u, __ATOMIC_ACQ_REL, __HIP_MEMORY_SCOPE_AGENT);
    if(a == GRP-1u){
      __hip_atomic_store(gcnt, 0u, __ATOMIC_RELAXED, __HIP_MEMORY_SCOPE_AGENT);
      u32 b = __hip_atomic_fetch_add(root, 1u, __ATOMIC_ACQ_REL, __HIP_MEMORY_SCOPE_AGENT);
      if(b == NGRP-1u){
        __hip_atomic_store(root, 0u, __ATOMIC_RELAXED, __HIP_MEMORY_SCOPE_AGENT);
        __hip_atomic_fetch_add(gen, 1u, __ATOMIC_RELEASE, __HIP_MEMORY_SCOPE_AGENT);
      }
    }
    while(__hip_atomic_load(gen, __ATOMIC_ACQUIRE, __HIP_MEMORY_SCOPE_AGENT)==g){
      __builtin_amdgcn_s_sleep(8);
    }
    __threadfence();
  }
  __syncthreads();
}

// group-local barrier: the 32 blocks of node-group xg.
__device__ __forceinline__ void gbar_grp(u32* bar, int xg){
  __syncthreads();
  if(threadIdx.x==0){
    __threadfence();
    u32* gcnt = bar + 512 + (xg<<4);
    u32* ggen = bar + 512 + (xg<<4) + 8;
    u32 g = __hip_atomic_load(ggen, __ATOMIC_RELAXED, __HIP_MEMORY_SCOPE_AGENT);
    u32 a = __hip_atomic_fetch_add(gcnt, 1u, __ATOMIC_ACQ_REL, __HIP_MEMORY_SCOPE_AGENT);
    if(a == 31u){
      __hip_atomic_store(gcnt, 0u, __ATOMIC_RELAXED, __HIP_MEMORY_SCOPE_AGENT);
      __hip_atomic_fetch_add(ggen, 1u, __ATOMIC_RELEASE, __HIP_MEMORY_SCOPE_AGENT);
    }else{
      while(__hip_atomic_load(ggen, __ATOMIC_ACQUIRE, __HIP_MEMORY_SCOPE_AGENT)==g){
        __builtin_amdgcn_s_sleep(4);
      }
    }
    __threadfence();
  }
  __syncthreads();
}

// combine two accumulator slots a,b across lane stride s.
__device__ __forceinline__ float comb(float a, float b, int s, int lane){
  const bool hi = (lane & s) != 0;
  float send = hi ? a : b;
  float sel  = hi ? b : a;
  return sel + __shfl_xor(send, s, 64);
}

__device__ __forceinline__ u32 packbf(float lo, float hi){
  u32 x=__float_as_uint(lo), y=__float_as_uint(hi);
  x = (x + 0x7fffu + ((x>>16)&1u)) >> 16;
  y = (y + 0x7fffu + ((y>>16)&1u)) & 0xffff0000u;
  return y | x;
}
__device__ __forceinline__ float bf_lo(u32 u){ return __uint_as_float(u<<16); }
__device__ __forceinline__ float bf_hi(u32 u){ return __uint_as_float(u & 0xffff0000u); }

#define PIN1(v) asm volatile("" : "+v"(v))

__global__ __launch_bounds__(1024,2) void k_rec(
    const int* __restrict__ parent,
    const float* __restrict__ Uz, const float* __restrict__ Ur, const float* __restrict__ Uh,
    float* __restrict__ wz, float* __restrict__ wr, float* __restrict__ wh,
    float* __restrict__ node_h,
    const int* __restrict__ meta, const int* __restrict__ lstart, const int* __restrict__ order,
    u32* __restrict__ bar){
  __shared__ float UhL[32*HID];      // 128 KB: this block's 32 rows of U_h (fp32)
  const int t=threadIdx.x, lane=t&63, wv=t>>6;   // 16 waves
  const int xg = blockIdx.x & 7;     // node-group (32 blocks)
  const int i  = blockIdx.x >> 3;    // 0..31 within group
  const bool isZ = wv < 8;           // waves 0-7: z-rows; 8-15: r-rows
  const int rA  = (i<<5) + ((wv&7)<<2);   // phase A: 4 rows per wave
  const int rC0 = i<<5;                   // phase C: block's 32 rows
  const int nlev = meta[0];
  const int l4 = lane<<2;

  // ---- one-time staging ----
  // 4 rows of Uz (waves 0-7) or Ur (waves 8-15) -> bf16-packed regs (32 u32).
  const float* UA = isZ ? Uz : Ur;
  u32 uap[4][8];
  #pragma unroll
  for(int r=0;r<4;r++)
    #pragma unroll
    for(int c=0;c<4;c++){
      const float4 v = *(const float4*)(UA + (size_t)(rA+r)*HID + (c<<8) + l4);
      uap[r][c*2]   = packbf(v.x, v.y);
      uap[r][c*2+1] = packbf(v.z, v.w);
      PIN1(uap[r][c*2]); PIN1(uap[r][c*2+1]);
    }
  // 32 rows of Uh -> fp32 LDS.
  for(int x=t; x<32*HID; x+=1024) UhL[x] = Uh[(size_t)rC0*HID + x];
  __syncthreads();

  for(int lev=0; lev<nlev; ++lev){
    const int s=lstart[lev];
    const int L=lstart[lev+1]-s;
    // ---- phase A: z rows (waves 0-7) and r rows (waves 8-15) ----
    {
      int jj = xg;
      int n=0, p=0; float4 bb[4];
      if(jj<L){
        n=order[s+jj]; p=parent[n];
        const float* ph = node_h + (size_t)p*HID;
        #pragma unroll
        for(int c=0;c<4;c++) bb[c] = *(const float4*)(ph + (c<<8) + l4);
      }
      while(jj<L){
        const int jn = jj+8;
        int n2=0, p2=0; float4 bb2[4];
        if(jn<L){
          n2=order[s+jn]; p2=parent[n2];
          const float* ph2 = node_h + (size_t)p2*HID;
          #pragma unroll
          for(int c=0;c<4;c++) bb2[c] = *(const float4*)(ph2 + (c<<8) + l4);
        }
        const int myrow = rA + (lane&3);
        float wv0 = isZ ? wz[(size_t)n*HID + myrow] : wr[(size_t)n*HID + myrow];
        float pv0 = isZ ? 0.f : node_h[(size_t)p*HID + myrow];
        float a0=0.f,a1=0.f,a2=0.f,a3=0.f;
        #pragma unroll
        for(int c=0;c<4;c++){
          const float4 b=bb[c];
          #define ROWFMA(acc,r) { const u32 p0=uap[r][c*2], p1=uap[r][c*2+1]; \
            acc=fmaf(bf_lo(p0),b.x,acc); acc=fmaf(bf_hi(p0),b.y,acc); \
            acc=fmaf(bf_lo(p1),b.z,acc); acc=fmaf(bf_hi(p1),b.w,acc); }
          ROWFMA(a0,0) ROWFMA(a1,1) ROWFMA(a2,2) ROWFMA(a3,3)
          #undef ROWFMA
        }
        float c0=comb(a0,a1,1,lane), c1=comb(a2,a3,1,lane);
        float v=comb(c0,c1,2,lane);
        v+=__shfl_xor(v,4,64); v+=__shfl_xor(v,8,64);
        v+=__shfl_xor(v,16,64); v+=__shfl_xor(v,32,64);
        if(lane<4){
          const size_t idx=(size_t)n*HID+myrow;
          if(isZ) wz[idx]=sigmf(wv0+v);
          else    wr[idx]=sigmf(wv0+v)*pv0;
        }
        jj=jn; n=n2; p=p2;
        #pragma unroll
        for(int c=0;c<4;c++) bb[c]=bb2[c];
      }
    }
    gbar_grp(bar, xg);   // this group produced all 1024 wz/wr rows it needs
    // ---- phase C: h-candidate + state update (2 rows/wave, fp32 Uh LDS) ----
    {
      int jj = xg;
      int n=0, p=0; float4 bb[4];
      if(jj<L){
        n=order[s+jj]; p=parent[n];
        const float* bw = wr + (size_t)n*HID;
        #pragma unroll
        for(int c=0;c<4;c++) bb[c] = *(const float4*)(bw + (c<<8) + l4);
      }
      while(jj<L){
        const int jn = jj+8;
        int n2=0, p2=0; float4 bb2[4];
        if(jn<L){
          n2=order[s+jn]; p2=parent[n2];
          const float* bw2 = wr + (size_t)n2*HID;
          #pragma unroll
          for(int c=0;c<4;c++) bb2[c] = *(const float4*)(bw2 + (c<<8) + l4);
        }
        const int myrow = rC0 + (wv<<1) + (lane&1);
        float zv0 = wz[(size_t)n*HID + myrow];
        float wh0 = wh[(size_t)n*HID + myrow];
        float pv0 = node_h[(size_t)p*HID + myrow];
        float a0=0.f,a1=0.f;
        #pragma unroll
        for(int c=0;c<4;c++){
          const float4 b=bb[c];
          const float4 u0 = *(const float4*)&UhL[((wv<<1)+0)*HID + (c<<8) + l4];
          const float4 u1 = *(const float4*)&UhL[((wv<<1)+1)*HID + (c<<8) + l4];
          a0=fmaf(u0.x,b.x,a0); a0=fmaf(u0.y,b.y,a0); a0=fmaf(u0.z,b.z,a0); a0=fmaf(u0.w,b.w,a0);
          a1=fmaf(u1.x,b.x,a1); a1=fmaf(u1.y,b.y,a1); a1=fmaf(u1.z,b.z,a1); a1=fmaf(u1.w,b.w,a1);
        }
        float v=comb(a0,a1,1,lane);
        v+=__shfl_xor(v,2,64); v+=__shfl_xor(v,4,64); v+=__shfl_xor(v,8,64);
        v+=__shfl_xor(v,16,64); v+=__shfl_xor(v,32,64);
        if(lane<2){
          const float c=tanhf(wh0+v);
          node_h[(size_t)(n+1)*HID+myrow]=zv0*pv0+(1.f-zv0)*c;
        }
        jj=jn; n=n2; p=p2;
        #pragma unroll
        for(int c=0;c<4;c++) bb[c]=bb2[c];
      }
    }
    gbar(bar);   // level boundary: parents cross groups -> global
  }
}

// ---------------------------------------------------------------------------
// Leaf max + softmax + loss. Output: FP32 pred[4], loss.
// ---------------------------------------------------------------------------
__global__ __launch_bounds__(1024) void k_final(const float* __restrict__ node_h,
                                                const int* __restrict__ leaf,
                                                const float* __restrict__ Wout,
                                                const float* __restrict__ bout,
                                                const float* __restrict__ y,
                                                float* __restrict__ out){
  __shared__ int li[NLEAVES];
  __shared__ float fs[HID];
  __shared__ float logits[NCLASS];
  const int t=threadIdx.x;
  li[t]=leaf[t];
  __syncthreads();
  float m=-INFINITY;
  for(int l=0;l<NLEAVES;l++) m = fmaxf(m, node_h[(size_t)li[l]*HID + t]);
  fs[t]=m;
  __syncthreads();
  const int wave=t>>6, lane=t&63;
  if(wave<NCLASS){
    float p=0.f;
    for(int h=lane;h<HID;h+=64) p += Wout[wave*HID+h]*fs[h];
    for(int off=32; off; off>>=1) p += __shfl_down(p, off);
    if(lane==0) logits[wave]=p+bout[wave];
  }
  __syncthreads();
  if(t==0){
    float mx = fmaxf(fmaxf(logits[0],logits[1]),fmaxf(logits[2],logits[3]));
    float ev[NCLASS]; float es=0.f;
    #pragma unroll
    for(int c=0;c<NCLASS;c++){ ev[c]=expf(logits[c]-mx); es+=ev[c]; }
    float loss=0.f;
    #pragma unroll
    for(int c=0;c<NCLASS;c++){
      float p=ev[c]/es;
      out[c]=p;
      float d=y[c]-p; loss+=d*d;
    }
    out[NCLASS]=loss;
  }
}

// ---------------------------------------------------------------------------
extern "C" void kernel_launch(void* const* d_in, const int* in_sizes, int n_in,
                              void* d_out, int out_size, void* d_ws, size_t ws_size,
                              hipStream_t stream){
  (void)in_sizes; (void)n_in; (void)out_size;
  const float* x_word=(const float*)d_in[0];
  const int*   x_index=(const int*)d_in[1];
  const int*   parent =(const int*)d_in[2];
  const int*   leaf   =(const int*)d_in[3];
  const float* y      =(const float*)d_in[4];
  const float* E      =(const float*)d_in[5];
  const float* W_z=(const float*)d_in[6];  const float* U_z=(const float*)d_in[7];  const float* b_z=(const float*)d_in[8];
  const float* W_r=(const float*)d_in[9];  const float* U_r=(const float*)d_in[10]; const float* b_r=(const float*)d_in[11];
  const float* W_h=(const float*)d_in[12]; const float* U_h=(const float*)d_in[13]; const float* b_h=(const float*)d_in[14];
  const float* W_out=(const float*)d_in[15]; const float* b_out=(const float*)d_in[16];

  size_t off=0;
  char* wsb=(char*)d_ws;
  auto alloc=[&](size_t b)->void*{ void* p=wsb+off; off=(off+b+255)&~(size_t)255; return p; };
  u32*  bar    = (u32*)  alloc(4096);
  int*  meta   = (int*)  alloc(256);
  int*  lstart = (int*)  alloc((N_NODES+1)*sizeof(int));
  int*  order  = (int*)  alloc(N_NODES*sizeof(int));
  float* node_h= (float*)alloc((size_t)(N_NODES+1)*HID*sizeof(float));
  float* xe    = (float*)alloc((size_t)N_NODES*HID*sizeof(float));
  float* wz    = (float*)alloc((size_t)N_NODES*HID*sizeof(float));
  float* wr    = (float*)alloc((size_t)N_NODES*HID*sizeof(float));
  float* wh    = (float*)alloc((size_t)N_NODES*HID*sizeof(float));
  float* ET    = (float*)(wsb+off);
  const size_t need_ET = off + (size_t)VOCAB*HID*sizeof(float);
  const bool useET = (ws_size >= need_ET);

  hipMemsetAsync(bar, 0, 4096, stream);
  k_levels<<<1,1024,0,stream>>>(parent, meta, lstart, order, node_h);
  if(useET){
    k_transpose<<<dim3((VOCAB+31)/32, HID/32),256,0,stream>>>(E, ET);
    k_xe<<<N_NODES,256,0,stream>>>(ET, x_word, x_index, xe);
  }else{
    k_xe_noET<<<N_NODES,256,0,stream>>>(E, x_word, x_index, xe);
  }
  k_gemm_in<<<dim3(N_NODES/64, HID/64, 3),256,0,stream>>>(xe, W_z,W_r,W_h, b_z,b_r,b_h, wz,wr,wh);
  k_rec<<<REC_GRID,1024,0,stream>>>(parent, U_z,U_r,U_h, wz,wr,wh, node_h, meta, lstart, order, bar);
  k_final<<<1,1024,0,stream>>>(node_h, leaf, W_out, b_out, y, (float*)d_out);
}

// Round 15
// 1419.808 us; speedup vs baseline: 5.4557x; 5.4557x over previous
//
#include <hip/hip_runtime.h>
#include <hip/hip_bf16.h>
#include <math.h>

#define N_NODES 4096
#define WPN 32
#define HID 1024
#define VOCAB 30000
#define NCLASS 4
#define NLEAVES 1024
#define MAXLEV 40

typedef unsigned int u32;
typedef unsigned short u16;
typedef __attribute__((ext_vector_type(8))) short short8v;
typedef __attribute__((ext_vector_type(4))) float f32x4;

__device__ __forceinline__ float sigmf(float x){ return 1.f/(1.f+expf(-x)); }
__device__ __forceinline__ u16 f2bf16(float f){
  u32 x=__float_as_uint(f);
  return (u16)((x + 0x7fffu + ((x>>16)&1u))>>16);
}

// ---------------------------------------------------------------------------
// Level schedule: depth[i] via iterative relaxation in LDS, then counting sort.
// Also zeroes node_h row 0 (root parent).
// ---------------------------------------------------------------------------
__global__ __launch_bounds__(1024) void k_levels(const int* __restrict__ parent,
                                                 int* __restrict__ meta,
                                                 int* __restrict__ lstart,
                                                 int* __restrict__ order,
                                                 float* __restrict__ node_h){
  __shared__ int dep[N_NODES];
  __shared__ int dpt[N_NODES];
  __shared__ int cnt[N_NODES];
  __shared__ int changed, maxd;
  const int t = threadIdx.x;
  for(int i=t;i<N_NODES;i+=1024){ dep[i]=parent[i]-1; dpt[i]=0; cnt[i]=0; }
  if(t==0){ maxd=0; }
  node_h[t]=0.f;  // 1024 threads == HID: zero root-parent row
  __syncthreads();
  while(true){
    if(t==0) changed=0;
    __syncthreads();
    bool ch=false;
    for(int i=t;i<N_NODES;i+=1024){
      int d = (dep[i]<0)? 0 : (dpt[dep[i]]+1);
      if(d>dpt[i]){ dpt[i]=d; ch=true; }
    }
    if(ch) changed=1;
    __syncthreads();
    if(!changed) break;
    __syncthreads();
  }
  __syncthreads();
  for(int i=t;i<N_NODES;i+=1024){ atomicAdd(&cnt[dpt[i]],1); atomicMax(&maxd,dpt[i]); }
  __syncthreads();
  int* sc = dep;
  for(int i=t;i<N_NODES;i+=1024) sc[i]=cnt[i];
  __syncthreads();
  for(int off=1; off<N_NODES; off<<=1){
    int v[4];
    #pragma unroll
    for(int u=0;u<4;u++){ int i=t+u*1024; v[u] = (i>=off)? sc[i-off] : 0; }
    __syncthreads();
    #pragma unroll
    for(int u=0;u<4;u++){ int i=t+u*1024; sc[i]+=v[u]; }
    __syncthreads();
  }
  for(int i=t;i<N_NODES;i+=1024) lstart[i+1]=sc[i];
  if(t==0){ lstart[0]=0; meta[0]=maxd+1; }
  for(int i=t;i<N_NODES;i+=1024) cnt[i]=sc[i]-cnt[i];
  __syncthreads();
  for(int i=t;i<N_NODES;i+=1024){
    int pos = atomicAdd(&cnt[dpt[i]],1);
    order[pos]=i;
  }
}

// ---------------------------------------------------------------------------
// U fp32 -> bf16 (one-time). grid (1024, 3), 256 thr, 4 elems/thr.
// ---------------------------------------------------------------------------
__global__ __launch_bounds__(256) void k_prep(const float* __restrict__ Uz,
                                              const float* __restrict__ Ur,
                                              const float* __restrict__ Uh,
                                              u16* __restrict__ Uzb,
                                              u16* __restrict__ Urb,
                                              u16* __restrict__ Uhb){
  const size_t i = ((size_t)blockIdx.x*256 + threadIdx.x)*4;
  const float* src = (blockIdx.y==0)?Uz:((blockIdx.y==1)?Ur:Uh);
  u16* dst = (blockIdx.y==0)?Uzb:((blockIdx.y==1)?Urb:Uhb);
  const float4 v = *(const float4*)(src+i);
  ushort4 o;
  o.x=f2bf16(v.x); o.y=f2bf16(v.y); o.z=f2bf16(v.z); o.w=f2bf16(v.w);
  *(ushort4*)(dst+i) = o;
}

// ---------------------------------------------------------------------------
// E [HID][VOCAB] f32  ->  ET [VOCAB][HID] f32  (tiled transpose)
// ---------------------------------------------------------------------------
__global__ __launch_bounds__(256) void k_transpose(const float* __restrict__ E,
                                                   float* __restrict__ ET){
  __shared__ float tile[32][33];
  const int v0 = blockIdx.x*32, h0 = blockIdx.y*32;
  const int tx = threadIdx.x%32, ty = threadIdx.x/32;
  #pragma unroll
  for(int i=0;i<4;i++){
    int h = h0+ty+8*i, v = v0+tx;
    tile[ty+8*i][tx] = (v<VOCAB)? E[(size_t)h*VOCAB + v] : 0.f;
  }
  __syncthreads();
  #pragma unroll
  for(int i=0;i<4;i++){
    int v = v0+ty+8*i, h = h0+tx;
    if(v<VOCAB) ET[(size_t)v*HID + h] = tile[tx][ty+8*i];
  }
}

// ---------------------------------------------------------------------------
// xe[n,h] = sum_l w[n,l] * ET[idx[n,l], h]
// ---------------------------------------------------------------------------
__global__ __launch_bounds__(256) void k_xe(const float* __restrict__ ET,
                                            const float* __restrict__ xw,
                                            const int* __restrict__ xi,
                                            float* __restrict__ xe){
  const int n = blockIdx.x;
  __shared__ float w[WPN]; __shared__ int id[WPN];
  const int t = threadIdx.x;
  if(t<WPN){ w[t]=xw[n*WPN+t]; id[t]=xi[n*WPN+t]; }
  __syncthreads();
  const int h0 = t*4;
  float a0=0,a1=0,a2=0,a3=0;
  for(int l=0;l<WPN;l++){
    const float4 e = *(const float4*)(ET + (size_t)id[l]*HID + h0);
    const float wl = w[l];
    a0 += wl*e.x; a1 += wl*e.y; a2 += wl*e.z; a3 += wl*e.w;
  }
  *(float4*)(xe + (size_t)n*HID + h0) = make_float4(a0,a1,a2,a3);
}

__global__ __launch_bounds__(256) void k_xe_noET(const float* __restrict__ E,
                                                 const float* __restrict__ xw,
                                                 const int* __restrict__ xi,
                                                 float* __restrict__ xe){
  const int n = blockIdx.x;
  __shared__ float w[WPN]; __shared__ int id[WPN];
  const int t = threadIdx.x;
  if(t<WPN){ w[t]=xw[n*WPN+t]; id[t]=xi[n*WPN+t]; }
  __syncthreads();
  const int h0 = t*4;
  float acc[4]={0,0,0,0};
  for(int l=0;l<WPN;l++){
    const float wl=w[l]; const int ix=id[l];
    #pragma unroll
    for(int j=0;j<4;j++) acc[j] += wl*E[(size_t)(h0+j)*VOCAB + ix];
  }
  *(float4*)(xe + (size_t)n*HID + h0) = make_float4(acc[0],acc[1],acc[2],acc[3]);
}

// ---------------------------------------------------------------------------
// Input-side projections (fp32 vector GEMM, unchanged).
// ---------------------------------------------------------------------------
__global__ __launch_bounds__(256) void k_gemm_in(const float* __restrict__ xe,
  const float* __restrict__ W0,const float* __restrict__ W1,const float* __restrict__ W2,
  const float* __restrict__ b0,const float* __restrict__ b1,const float* __restrict__ b2,
  float* __restrict__ o0p,float* __restrict__ o1p,float* __restrict__ o2p){
  __shared__ float A[32*68];
  __shared__ float B[32*68];
  const int g=blockIdx.z;
  const float* W  = (g==0)?W0:((g==1)?W1:W2);
  const float* bi = (g==0)?b0:((g==1)?b1:b2);
  float* out      = (g==0)?o0p:((g==1)?o1p:o2p);
  const int n0=blockIdx.x<<6, q0=blockIdx.y<<6;
  const int t=threadIdx.x, tx=t&15, ty=t>>4;
  float acc[4][4]={};
  for(int k0=0;k0<HID;k0+=32){
    #pragma unroll
    for(int m=0;m<2;m++){
      int idx=t+(m<<8); int r=idx>>3; int c4=(idx&7)<<2;
      float4 v=*(const float4*)(xe+(size_t)(n0+r)*HID+k0+c4);
      A[(c4+0)*68+r]=v.x; A[(c4+1)*68+r]=v.y; A[(c4+2)*68+r]=v.z; A[(c4+3)*68+r]=v.w;
      float4 u=*(const float4*)(W+(size_t)(q0+r)*HID+k0+c4);
      B[(c4+0)*68+r]=u.x; B[(c4+1)*68+r]=u.y; B[(c4+2)*68+r]=u.z; B[(c4+3)*68+r]=u.w;
    }
    __syncthreads();
    #pragma unroll 8
    for(int k=0;k<32;k++){
      const float4 a=*(const float4*)&A[k*68+(ty<<2)];
      const float4 b=*(const float4*)&B[k*68+(tx<<2)];
      acc[0][0]+=a.x*b.x; acc[0][1]+=a.x*b.y; acc[0][2]+=a.x*b.z; acc[0][3]+=a.x*b.w;
      acc[1][0]+=a.y*b.x; acc[1][1]+=a.y*b.y; acc[1][2]+=a.y*b.z; acc[1][3]+=a.y*b.w;
      acc[2][0]+=a.z*b.x; acc[2][1]+=a.z*b.y; acc[2][2]+=a.z*b.z; acc[2][3]+=a.z*b.w;
      acc[3][0]+=a.w*b.x; acc[3][1]+=a.w*b.y; acc[3][2]+=a.w*b.z; acc[3][3]+=a.w*b.w;
    }
    __syncthreads();
  }
  const float4 bb=*(const float4*)(bi+q0+(tx<<2));
  #pragma unroll
  for(int i=0;i<4;i++){
    const int n=n0+(ty<<2)+i;
    float4 r4 = make_float4(acc[i][0]+bb.x, acc[i][1]+bb.y, acc[i][2]+bb.z, acc[i][3]+bb.w);
    *(float4*)(out+(size_t)n*HID+q0+(tx<<2)) = r4;
  }
}

// ---------------------------------------------------------------------------
// v15 recurrence: per-level MFMA GEMM kernels. No persistence, no grid
// barriers (kernel boundaries sync), no pinned registers (tier law dodged).
// Tile: 32 rows x 32 cols, BK=32, 256 thr = 4 waves, each wave one 16x16
// quadrant via mfma_f32_16x16x32_bf16. LDS padded stride 40 bf16.
// A-frag: row=lane&15, k=(lane>>4)*8+e (k-contiguous); C/D: col=lane&15,
// row=(lane>>4)*4+reg (HW-verified mapping).
// ---------------------------------------------------------------------------
__global__ void k_lvlA(const float* __restrict__ node_h,
                       const u16* __restrict__ Uzb, const u16* __restrict__ Urb,
                       float* __restrict__ wz, float* __restrict__ wr,
                       const int* __restrict__ parent,
                       const int* __restrict__ lstart, const int* __restrict__ order,
                       int lev){
  const int s = lstart[lev];
  const int L = lstart[lev+1] - s;
  const int j0 = blockIdx.y<<5;
  if(j0 >= L) return;
  const int m0 = blockIdx.x<<5;
  const int gate = blockIdx.z;
  const u16* U = gate? Urb : Uzb;
  __shared__ __align__(16) u16 As[32*40];
  __shared__ __align__(16) u16 Bs[32*40];
  __shared__ int nds[32], pds[32];
  const int t=threadIdx.x, lane=t&63, w=t>>6;
  if(t<32){
    const int j=j0+t;
    const int n=(j<L)? order[s+j] : 0;
    nds[t]=n; pds[t]=(j<L)? parent[n] : 0;
  }
  __syncthreads();
  const int srow=t>>3, sk4=(t&7)<<2;           // staging: row/col 0..31, k-quad
  const float* bp = node_h + (size_t)pds[srow]*HID;
  const u16*   ap = U + (size_t)(m0+srow)*HID;
  const int qr=w&1, qc=w>>1;
  f32x4 acc = {0.f,0.f,0.f,0.f};
  const int afo = (16*qr + (lane&15))*40 + ((lane>>4)<<3);
  const int bfo = (16*qc + (lane&15))*40 + ((lane>>4)<<3);
  for(int k0=0;k0<HID;k0+=32){
    *(ushort4*)&As[srow*40 + sk4] = *(const ushort4*)(ap + k0 + sk4);
    const float4 bv = *(const float4*)(bp + k0 + sk4);
    ushort4 bw;
    bw.x=f2bf16(bv.x); bw.y=f2bf16(bv.y); bw.z=f2bf16(bv.z); bw.w=f2bf16(bv.w);
    *(ushort4*)&Bs[srow*40 + sk4] = bw;
    __syncthreads();
    const short8v af = *(const short8v*)&As[afo];
    const short8v bf = *(const short8v*)&Bs[bfo];
    acc = __builtin_amdgcn_mfma_f32_16x16x32_bf16(af, bf, acc, 0,0,0);
    __syncthreads();
  }
  const int jl = 16*qc + (lane&15);
  if(j0 + jl < L){
    const int n = nds[jl], p = pds[jl];
    const int mb = m0 + 16*qr + ((lane>>4)<<2);
    if(gate==0){
      float4 wv = *(float4*)(wz + (size_t)n*HID + mb);
      wv.x=sigmf(wv.x+acc[0]); wv.y=sigmf(wv.y+acc[1]);
      wv.z=sigmf(wv.z+acc[2]); wv.w=sigmf(wv.w+acc[3]);
      *(float4*)(wz + (size_t)n*HID + mb) = wv;
    }else{
      float4 wv = *(float4*)(wr + (size_t)n*HID + mb);
      const float4 ph = *(const float4*)(node_h + (size_t)p*HID + mb);
      wv.x=sigmf(wv.x+acc[0])*ph.x; wv.y=sigmf(wv.y+acc[1])*ph.y;
      wv.z=sigmf(wv.z+acc[2])*ph.z; wv.w=sigmf(wv.w+acc[3])*ph.w;
      *(float4*)(wr + (size_t)n*HID + mb) = wv;
    }
  }
}

__global__ void k_lvlC(float* __restrict__ node_h,
                       const u16* __restrict__ Uhb,
                       const float* __restrict__ wz, const float* __restrict__ wr,
                       const float* __restrict__ wh,
                       const int* __restrict__ parent,
                       const int* __restrict__ lstart, const int* __restrict__ order,
                       int lev){
  const int s = lstart[lev];
  const int L = lstart[lev+1] - s;
  const int j0 = blockIdx.y<<5;
  if(j0 >= L) return;
  const int m0 = blockIdx.x<<5;
  __shared__ __align__(16) u16 As[32*40];
  __shared__ __align__(16) u16 Bs[32*40];
  __shared__ int nds[32], pds[32];
  const int t=threadIdx.x, lane=t&63, w=t>>6;
  if(t<32){
    const int j=j0+t;
    const int n=(j<L)? order[s+j] : 0;
    nds[t]=n; pds[t]=(j<L)? parent[n] : 0;
  }
  __syncthreads();
  const int srow=t>>3, sk4=(t&7)<<2;
  const float* bp = wr + (size_t)nds[srow]*HID;
  const u16*   ap = Uhb + (size_t)(m0+srow)*HID;
  const int qr=w&1, qc=w>>1;
  f32x4 acc = {0.f,0.f,0.f,0.f};
  const int afo = (16*qr + (lane&15))*40 + ((lane>>4)<<3);
  const int bfo = (16*qc + (lane&15))*40 + ((lane>>4)<<3);
  for(int k0=0;k0<HID;k0+=32){
    *(ushort4*)&As[srow*40 + sk4] = *(const ushort4*)(ap + k0 + sk4);
    const float4 bv = *(const float4*)(bp + k0 + sk4);
    ushort4 bw;
    bw.x=f2bf16(bv.x); bw.y=f2bf16(bv.y); bw.z=f2bf16(bv.z); bw.w=f2bf16(bv.w);
    *(ushort4*)&Bs[srow*40 + sk4] = bw;
    __syncthreads();
    const short8v af = *(const short8v*)&As[afo];
    const short8v bf = *(const short8v*)&Bs[bfo];
    acc = __builtin_amdgcn_mfma_f32_16x16x32_bf16(af, bf, acc, 0,0,0);
    __syncthreads();
  }
  const int jl = 16*qc + (lane&15);
  if(j0 + jl < L){
    const int n = nds[jl], p = pds[jl];
    const int mb = m0 + 16*qr + ((lane>>4)<<2);
    const float4 whv = *(const float4*)(wh + (size_t)n*HID + mb);
    const float4 z4  = *(const float4*)(wz + (size_t)n*HID + mb);
    const float4 ph  = *(const float4*)(node_h + (size_t)p*HID + mb);
    float4 hn;
    hn.x = z4.x*ph.x + (1.f-z4.x)*tanhf(whv.x+acc[0]);
    hn.y = z4.y*ph.y + (1.f-z4.y)*tanhf(whv.y+acc[1]);
    hn.z = z4.z*ph.z + (1.f-z4.z)*tanhf(whv.z+acc[2]);
    hn.w = z4.w*ph.w + (1.f-z4.w)*tanhf(whv.w+acc[3]);
    *(float4*)(node_h + (size_t)(n+1)*HID + mb) = hn;
  }
}

// ---------------------------------------------------------------------------
// Leaf max + softmax + loss. Output: FP32 pred[4], loss.
// ---------------------------------------------------------------------------
__global__ __launch_bounds__(1024) void k_final(const float* __restrict__ node_h,
                                                const int* __restrict__ leaf,
                                                const float* __restrict__ Wout,
                                                const float* __restrict__ bout,
                                                const float* __restrict__ y,
                                                float* __restrict__ out){
  __shared__ int li[NLEAVES];
  __shared__ float fs[HID];
  __shared__ float logits[NCLASS];
  const int t=threadIdx.x;
  li[t]=leaf[t];
  __syncthreads();
  float m=-INFINITY;
  for(int l=0;l<NLEAVES;l++) m = fmaxf(m, node_h[(size_t)li[l]*HID + t]);
  fs[t]=m;
  __syncthreads();
  const int wave=t>>6, lane=t&63;
  if(wave<NCLASS){
    float p=0.f;
    for(int h=lane;h<HID;h+=64) p += Wout[wave*HID+h]*fs[h];
    for(int off=32; off; off>>=1) p += __shfl_down(p, off);
    if(lane==0) logits[wave]=p+bout[wave];
  }
  __syncthreads();
  if(t==0){
    float mx = fmaxf(fmaxf(logits[0],logits[1]),fmaxf(logits[2],logits[3]));
    float ev[NCLASS]; float es=0.f;
    #pragma unroll
    for(int c=0;c<NCLASS;c++){ ev[c]=expf(logits[c]-mx); es+=ev[c]; }
    float loss=0.f;
    #pragma unroll
    for(int c=0;c<NCLASS;c++){
      float p=ev[c]/es;
      out[c]=p;
      float d=y[c]-p; loss+=d*d;
    }
    out[NCLASS]=loss;
  }
}

// ---------------------------------------------------------------------------
extern "C" void kernel_launch(void* const* d_in, const int* in_sizes, int n_in,
                              void* d_out, int out_size, void* d_ws, size_t ws_size,
                              hipStream_t stream){
  (void)in_sizes; (void)n_in; (void)out_size;
  const float* x_word=(const float*)d_in[0];
  const int*   x_index=(const int*)d_in[1];
  const int*   parent =(const int*)d_in[2];
  const int*   leaf   =(const int*)d_in[3];
  const float* y      =(const float*)d_in[4];
  const float* E      =(const float*)d_in[5];
  const float* W_z=(const float*)d_in[6];  const float* U_z=(const float*)d_in[7];  const float* b_z=(const float*)d_in[8];
  const float* W_r=(const float*)d_in[9];  const float* U_r=(const float*)d_in[10]; const float* b_r=(const float*)d_in[11];
  const float* W_h=(const float*)d_in[12]; const float* U_h=(const float*)d_in[13]; const float* b_h=(const float*)d_in[14];
  const float* W_out=(const float*)d_in[15]; const float* b_out=(const float*)d_in[16];

  size_t off=0;
  char* wsb=(char*)d_ws;
  auto alloc=[&](size_t b)->void*{ void* p=wsb+off; off=(off+b+255)&~(size_t)255; return p; };
  int*  meta   = (int*)  alloc(256);
  int*  lstart = (int*)  alloc((N_NODES+1)*sizeof(int));
  int*  order  = (int*)  alloc(N_NODES*sizeof(int));
  float* node_h= (float*)alloc((size_t)(N_NODES+1)*HID*sizeof(float));
  float* xe    = (float*)alloc((size_t)N_NODES*HID*sizeof(float));
  float* wz    = (float*)alloc((size_t)N_NODES*HID*sizeof(float));
  float* wr    = (float*)alloc((size_t)N_NODES*HID*sizeof(float));
  float* wh    = (float*)alloc((size_t)N_NODES*HID*sizeof(float));
  u16*  Uzb    = (u16*)  alloc((size_t)HID*HID*sizeof(u16));
  u16*  Urb    = (u16*)  alloc((size_t)HID*HID*sizeof(u16));
  u16*  Uhb    = (u16*)  alloc((size_t)HID*HID*sizeof(u16));
  float* ET    = (float*)(wsb+off);
  const size_t need_ET = off + (size_t)VOCAB*HID*sizeof(float);
  const bool useET = (ws_size >= need_ET);

  k_levels<<<1,1024,0,stream>>>(parent, meta, lstart, order, node_h);
  k_prep<<<dim3(1024,3),256,0,stream>>>(U_z,U_r,U_h, Uzb,Urb,Uhb);
  if(useET){
    k_transpose<<<dim3((VOCAB+31)/32, HID/32),256,0,stream>>>(E, ET);
    k_xe<<<N_NODES,256,0,stream>>>(ET, x_word, x_index, xe);
  }else{
    k_xe_noET<<<N_NODES,256,0,stream>>>(E, x_word, x_index, xe);
  }
  k_gemm_in<<<dim3(N_NODES/64, HID/64, 3),256,0,stream>>>(xe, W_z,W_r,W_h, b_z,b_r,b_h, wz,wr,wh);
  for(int lev=0; lev<MAXLEV; ++lev){
    k_lvlA<<<dim3(HID/32, 24, 2),256,0,stream>>>(node_h, Uzb,Urb, wz,wr, parent, lstart, order, lev);
    k_lvlC<<<dim3(HID/32, 24),256,0,stream>>>(node_h, Uhb, wz,wr,wh, parent, lstart, order, lev);
  }
  k_final<<<1,1024,0,stream>>>(node_h, leaf, W_out, b_out, y, (float*)d_out);
}

// Round 16
// 1140.245 us; speedup vs baseline: 6.7933x; 1.2452x over previous
//
#include <hip/hip_runtime.h>
#include <hip/hip_bf16.h>
#include <math.h>

#define N_NODES 4096
#define WPN 32
#define HID 1024
#define VOCAB 30000
#define NCLASS 4
#define NLEAVES 1024
#define MAXLEV 40

typedef unsigned int u32;
typedef unsigned short u16;
typedef __attribute__((ext_vector_type(8))) short short8v;
typedef __attribute__((ext_vector_type(4))) float f32x4;

__device__ __forceinline__ float sigmf(float x){ return 1.f/(1.f+expf(-x)); }
__device__ __forceinline__ u16 f2bf16(float f){
  u32 x=__float_as_uint(f);
  return (u16)((x + 0x7fffu + ((x>>16)&1u))>>16);
}

// ---------------------------------------------------------------------------
// Level schedule (unchanged).
// ---------------------------------------------------------------------------
__global__ __launch_bounds__(1024) void k_levels(const int* __restrict__ parent,
                                                 int* __restrict__ meta,
                                                 int* __restrict__ lstart,
                                                 int* __restrict__ order,
                                                 float* __restrict__ node_h){
  __shared__ int dep[N_NODES];
  __shared__ int dpt[N_NODES];
  __shared__ int cnt[N_NODES];
  __shared__ int changed, maxd;
  const int t = threadIdx.x;
  for(int i=t;i<N_NODES;i+=1024){ dep[i]=parent[i]-1; dpt[i]=0; cnt[i]=0; }
  if(t==0){ maxd=0; }
  node_h[t]=0.f;
  __syncthreads();
  while(true){
    if(t==0) changed=0;
    __syncthreads();
    bool ch=false;
    for(int i=t;i<N_NODES;i+=1024){
      int d = (dep[i]<0)? 0 : (dpt[dep[i]]+1);
      if(d>dpt[i]){ dpt[i]=d; ch=true; }
    }
    if(ch) changed=1;
    __syncthreads();
    if(!changed) break;
    __syncthreads();
  }
  __syncthreads();
  for(int i=t;i<N_NODES;i+=1024){ atomicAdd(&cnt[dpt[i]],1); atomicMax(&maxd,dpt[i]); }
  __syncthreads();
  int* sc = dep;
  for(int i=t;i<N_NODES;i+=1024) sc[i]=cnt[i];
  __syncthreads();
  for(int off=1; off<N_NODES; off<<=1){
    int v[4];
    #pragma unroll
    for(int u=0;u<4;u++){ int i=t+u*1024; v[u] = (i>=off)? sc[i-off] : 0; }
    __syncthreads();
    #pragma unroll
    for(int u=0;u<4;u++){ int i=t+u*1024; sc[i]+=v[u]; }
    __syncthreads();
  }
  for(int i=t;i<N_NODES;i+=1024) lstart[i+1]=sc[i];
  if(t==0){ lstart[0]=0; meta[0]=maxd+1; }
  for(int i=t;i<N_NODES;i+=1024) cnt[i]=sc[i]-cnt[i];
  __syncthreads();
  for(int i=t;i<N_NODES;i+=1024){
    int pos = atomicAdd(&cnt[dpt[i]],1);
    order[pos]=i;
  }
}

// ---------------------------------------------------------------------------
// fp32 -> bf16 one-time: W_z,W_r,W_h,U_z,U_r,U_h. grid (1024,6).
// ---------------------------------------------------------------------------
__global__ __launch_bounds__(256) void k_prep(const float* __restrict__ Wz,
                                              const float* __restrict__ Wr,
                                              const float* __restrict__ Wh,
                                              const float* __restrict__ Uz,
                                              const float* __restrict__ Ur,
                                              const float* __restrict__ Uh,
                                              u16* __restrict__ Wzb, u16* __restrict__ Wrb,
                                              u16* __restrict__ Whb, u16* __restrict__ Uzb,
                                              u16* __restrict__ Urb, u16* __restrict__ Uhb){
  const size_t i = ((size_t)blockIdx.x*256 + threadIdx.x)*4;
  const float* srcs[6]={Wz,Wr,Wh,Uz,Ur,Uh};
  u16* dsts[6]={Wzb,Wrb,Whb,Uzb,Urb,Uhb};
  const float* src = srcs[blockIdx.y];
  u16* dst = dsts[blockIdx.y];
  const float4 v = *(const float4*)(src+i);
  ushort4 o;
  o.x=f2bf16(v.x); o.y=f2bf16(v.y); o.z=f2bf16(v.z); o.w=f2bf16(v.w);
  *(ushort4*)(dst+i) = o;
}

// ---------------------------------------------------------------------------
// E [HID][VOCAB] f32  ->  ET [VOCAB][HID] f32  (tiled transpose)
// ---------------------------------------------------------------------------
__global__ __launch_bounds__(256) void k_transpose(const float* __restrict__ E,
                                                   float* __restrict__ ET){
  __shared__ float tile[32][33];
  const int v0 = blockIdx.x*32, h0 = blockIdx.y*32;
  const int tx = threadIdx.x%32, ty = threadIdx.x/32;
  #pragma unroll
  for(int i=0;i<4;i++){
    int h = h0+ty+8*i, v = v0+tx;
    tile[ty+8*i][tx] = (v<VOCAB)? E[(size_t)h*VOCAB + v] : 0.f;
  }
  __syncthreads();
  #pragma unroll
  for(int i=0;i<4;i++){
    int v = v0+ty+8*i, h = h0+tx;
    if(v<VOCAB) ET[(size_t)v*HID + h] = tile[tx][ty+8*i];
  }
}

// ---------------------------------------------------------------------------
// xe (bf16 out): xeb[n,h] = bf16( sum_l w[n,l] * ET[idx[n,l], h] )
// ---------------------------------------------------------------------------
__global__ __launch_bounds__(256) void k_xe(const float* __restrict__ ET,
                                            const float* __restrict__ xw,
                                            const int* __restrict__ xi,
                                            u16* __restrict__ xeb){
  const int n = blockIdx.x;
  __shared__ float w[WPN]; __shared__ int id[WPN];
  const int t = threadIdx.x;
  if(t<WPN){ w[t]=xw[n*WPN+t]; id[t]=xi[n*WPN+t]; }
  __syncthreads();
  const int h0 = t*4;
  float a0=0,a1=0,a2=0,a3=0;
  for(int l=0;l<WPN;l++){
    const float4 e = *(const float4*)(ET + (size_t)id[l]*HID + h0);
    const float wl = w[l];
    a0 += wl*e.x; a1 += wl*e.y; a2 += wl*e.z; a3 += wl*e.w;
  }
  ushort4 o; o.x=f2bf16(a0); o.y=f2bf16(a1); o.z=f2bf16(a2); o.w=f2bf16(a3);
  *(ushort4*)(xeb + (size_t)n*HID + h0) = o;
}

__global__ __launch_bounds__(256) void k_xe_noET(const float* __restrict__ E,
                                                 const float* __restrict__ xw,
                                                 const int* __restrict__ xi,
                                                 u16* __restrict__ xeb){
  const int n = blockIdx.x;
  __shared__ float w[WPN]; __shared__ int id[WPN];
  const int t = threadIdx.x;
  if(t<WPN){ w[t]=xw[n*WPN+t]; id[t]=xi[n*WPN+t]; }
  __syncthreads();
  const int h0 = t*4;
  float acc[4]={0,0,0,0};
  for(int l=0;l<WPN;l++){
    const float wl=w[l]; const int ix=id[l];
    #pragma unroll
    for(int j=0;j<4;j++) acc[j] += wl*E[(size_t)(h0+j)*VOCAB + ix];
  }
  ushort4 o; o.x=f2bf16(acc[0]); o.y=f2bf16(acc[1]); o.z=f2bf16(acc[2]); o.w=f2bf16(acc[3]);
  *(ushort4*)(xeb + (size_t)n*HID + h0) = o;
}

// ---------------------------------------------------------------------------
// v16 input projections: MFMA bf16. out_g[n,o] = b_g[o] + sum_k xe[n,k]W_g[o,k]
// 64x64 tile, BK=32, 4 waves x (32x32 quadrant = 2x2 mfma frags).
// Same verified frag/CD mapping as k_lvlA. LDS stride 40 (no conflicts).
// ---------------------------------------------------------------------------
__global__ __launch_bounds__(256) void k_gemm_in(const u16* __restrict__ xeb,
  const u16* __restrict__ W0,const u16* __restrict__ W1,const u16* __restrict__ W2,
  const float* __restrict__ b0,const float* __restrict__ b1,const float* __restrict__ b2,
  float* __restrict__ o0p,float* __restrict__ o1p,float* __restrict__ o2p){
  const int g=blockIdx.z;
  const u16* W    = (g==0)?W0:((g==1)?W1:W2);
  const float* bi = (g==0)?b0:((g==1)?b1:b2);
  float* out      = (g==0)?o0p:((g==1)?o1p:o2p);
  const int m0=blockIdx.x<<6;          // 64 o-rows
  const int n0=blockIdx.y<<6;          // 64 nodes
  __shared__ __align__(16) u16 As[64*40];
  __shared__ __align__(16) u16 Bs[64*40];
  const int t=threadIdx.x, lane=t&63, w=t>>6;
  const int srow=t>>2, sk8=(t&3)<<3;   // staging: row 0..63, 8 bf16
  const u16* ap = W   + (size_t)(m0+srow)*HID + sk8;
  const u16* bp = xeb + (size_t)(n0+srow)*HID + sk8;
  const int qr=w&1, qc=w>>1;
  f32x4 acc[2][2]={};
  const int abase = (qr<<5)*40, bbase = (qc<<5)*40;
  const int lrow=(lane&15)*40, lk=((lane>>4)<<3);
  for(int k0=0;k0<HID;k0+=32){
    *(short8v*)&As[srow*40 + sk8] = *(const short8v*)(ap + k0);
    *(short8v*)&Bs[srow*40 + sk8] = *(const short8v*)(bp + k0);
    __syncthreads();
    short8v af0 = *(const short8v*)&As[abase + lrow + lk];
    short8v af1 = *(const short8v*)&As[abase + 16*40 + lrow + lk];
    short8v bf0 = *(const short8v*)&Bs[bbase + lrow + lk];
    short8v bf1 = *(const short8v*)&Bs[bbase + 16*40 + lrow + lk];
    acc[0][0]=__builtin_amdgcn_mfma_f32_16x16x32_bf16(af0,bf0,acc[0][0],0,0,0);
    acc[0][1]=__builtin_amdgcn_mfma_f32_16x16x32_bf16(af0,bf1,acc[0][1],0,0,0);
    acc[1][0]=__builtin_amdgcn_mfma_f32_16x16x32_bf16(af1,bf0,acc[1][0],0,0,0);
    acc[1][1]=__builtin_amdgcn_mfma_f32_16x16x32_bf16(af1,bf1,acc[1][1],0,0,0);
    __syncthreads();
  }
  #pragma unroll
  for(int fi=0;fi<2;fi++){
    const int o = m0 + (qr<<5) + fi*16 + ((lane>>4)<<2);
    const float4 bb = *(const float4*)(bi + o);
    #pragma unroll
    for(int fj=0;fj<2;fj++){
      const int n = n0 + (qc<<5) + fj*16 + (lane&15);
      float4 r4 = make_float4(acc[fi][fj][0]+bb.x, acc[fi][fj][1]+bb.y,
                              acc[fi][fj][2]+bb.z, acc[fi][fj][3]+bb.w);
      *(float4*)(out + (size_t)n*HID + o) = r4;
    }
  }
}

// ---------------------------------------------------------------------------
// v15 recurrence kernels (unchanged — proven absmax 0.0).
// ---------------------------------------------------------------------------
__global__ void k_lvlA(const float* __restrict__ node_h,
                       const u16* __restrict__ Uzb, const u16* __restrict__ Urb,
                       float* __restrict__ wz, float* __restrict__ wr,
                       const int* __restrict__ parent,
                       const int* __restrict__ lstart, const int* __restrict__ order,
                       int lev){
  const int s = lstart[lev];
  const int L = lstart[lev+1] - s;
  const int j0 = blockIdx.y<<5;
  if(j0 >= L) return;
  const int m0 = blockIdx.x<<5;
  const int gate = blockIdx.z;
  const u16* U = gate? Urb : Uzb;
  __shared__ __align__(16) u16 As[32*40];
  __shared__ __align__(16) u16 Bs[32*40];
  __shared__ int nds[32], pds[32];
  const int t=threadIdx.x, lane=t&63, w=t>>6;
  if(t<32){
    const int j=j0+t;
    const int n=(j<L)? order[s+j] : 0;
    nds[t]=n; pds[t]=(j<L)? parent[n] : 0;
  }
  __syncthreads();
  const int srow=t>>3, sk4=(t&7)<<2;
  const float* bp = node_h + (size_t)pds[srow]*HID;
  const u16*   ap = U + (size_t)(m0+srow)*HID;
  const int qr=w&1, qc=w>>1;
  f32x4 acc = {0.f,0.f,0.f,0.f};
  const int afo = (16*qr + (lane&15))*40 + ((lane>>4)<<3);
  const int bfo = (16*qc + (lane&15))*40 + ((lane>>4)<<3);
  for(int k0=0;k0<HID;k0+=32){
    *(ushort4*)&As[srow*40 + sk4] = *(const ushort4*)(ap + k0 + sk4);
    const float4 bv = *(const float4*)(bp + k0 + sk4);
    ushort4 bw;
    bw.x=f2bf16(bv.x); bw.y=f2bf16(bv.y); bw.z=f2bf16(bv.z); bw.w=f2bf16(bv.w);
    *(ushort4*)&Bs[srow*40 + sk4] = bw;
    __syncthreads();
    const short8v af = *(const short8v*)&As[afo];
    const short8v bf = *(const short8v*)&Bs[bfo];
    acc = __builtin_amdgcn_mfma_f32_16x16x32_bf16(af, bf, acc, 0,0,0);
    __syncthreads();
  }
  const int jl = 16*qc + (lane&15);
  if(j0 + jl < L){
    const int n = nds[jl], p = pds[jl];
    const int mb = m0 + 16*qr + ((lane>>4)<<2);
    if(gate==0){
      float4 wv = *(float4*)(wz + (size_t)n*HID + mb);
      wv.x=sigmf(wv.x+acc[0]); wv.y=sigmf(wv.y+acc[1]);
      wv.z=sigmf(wv.z+acc[2]); wv.w=sigmf(wv.w+acc[3]);
      *(float4*)(wz + (size_t)n*HID + mb) = wv;
    }else{
      float4 wv = *(float4*)(wr + (size_t)n*HID + mb);
      const float4 ph = *(const float4*)(node_h + (size_t)p*HID + mb);
      wv.x=sigmf(wv.x+acc[0])*ph.x; wv.y=sigmf(wv.y+acc[1])*ph.y;
      wv.z=sigmf(wv.z+acc[2])*ph.z; wv.w=sigmf(wv.w+acc[3])*ph.w;
      *(float4*)(wr + (size_t)n*HID + mb) = wv;
    }
  }
}

__global__ void k_lvlC(float* __restrict__ node_h,
                       const u16* __restrict__ Uhb,
                       const float* __restrict__ wz, const float* __restrict__ wr,
                       const float* __restrict__ wh,
                       const int* __restrict__ parent,
                       const int* __restrict__ lstart, const int* __restrict__ order,
                       int lev){
  const int s = lstart[lev];
  const int L = lstart[lev+1] - s;
  const int j0 = blockIdx.y<<5;
  if(j0 >= L) return;
  const int m0 = blockIdx.x<<5;
  __shared__ __align__(16) u16 As[32*40];
  __shared__ __align__(16) u16 Bs[32*40];
  __shared__ int nds[32], pds[32];
  const int t=threadIdx.x, lane=t&63, w=t>>6;
  if(t<32){
    const int j=j0+t;
    const int n=(j<L)? order[s+j] : 0;
    nds[t]=n; pds[t]=(j<L)? parent[n] : 0;
  }
  __syncthreads();
  const int srow=t>>3, sk4=(t&7)<<2;
  const float* bp = wr + (size_t)nds[srow]*HID;
  const u16*   ap = Uhb + (size_t)(m0+srow)*HID;
  const int qr=w&1, qc=w>>1;
  f32x4 acc = {0.f,0.f,0.f,0.f};
  const int afo = (16*qr + (lane&15))*40 + ((lane>>4)<<3);
  const int bfo = (16*qc + (lane&15))*40 + ((lane>>4)<<3);
  for(int k0=0;k0<HID;k0+=32){
    *(ushort4*)&As[srow*40 + sk4] = *(const ushort4*)(ap + k0 + sk4);
    const float4 bv = *(const float4*)(bp + k0 + sk4);
    ushort4 bw;
    bw.x=f2bf16(bv.x); bw.y=f2bf16(bv.y); bw.z=f2bf16(bv.z); bw.w=f2bf16(bv.w);
    *(ushort4*)&Bs[srow*40 + sk4] = bw;
    __syncthreads();
    const short8v af = *(const short8v*)&As[afo];
    const short8v bf = *(const short8v*)&Bs[bfo];
    acc = __builtin_amdgcn_mfma_f32_16x16x32_bf16(af, bf, acc, 0,0,0);
    __syncthreads();
  }
  const int jl = 16*qc + (lane&15);
  if(j0 + jl < L){
    const int n = nds[jl], p = pds[jl];
    const int mb = m0 + 16*qr + ((lane>>4)<<2);
    const float4 whv = *(const float4*)(wh + (size_t)n*HID + mb);
    const float4 z4  = *(const float4*)(wz + (size_t)n*HID + mb);
    const float4 ph  = *(const float4*)(node_h + (size_t)p*HID + mb);
    float4 hn;
    hn.x = z4.x*ph.x + (1.f-z4.x)*tanhf(whv.x+acc[0]);
    hn.y = z4.y*ph.y + (1.f-z4.y)*tanhf(whv.y+acc[1]);
    hn.z = z4.z*ph.z + (1.f-z4.z)*tanhf(whv.z+acc[2]);
    hn.w = z4.w*ph.w + (1.f-z4.w)*tanhf(whv.w+acc[3]);
    *(float4*)(node_h + (size_t)(n+1)*HID + mb) = hn;
  }
}

// ---------------------------------------------------------------------------
// Leaf max + softmax + loss. Output: FP32 pred[4], loss.
// ---------------------------------------------------------------------------
__global__ __launch_bounds__(1024) void k_final(const float* __restrict__ node_h,
                                                const int* __restrict__ leaf,
                                                const float* __restrict__ Wout,
                                                const float* __restrict__ bout,
                                                const float* __restrict__ y,
                                                float* __restrict__ out){
  __shared__ int li[NLEAVES];
  __shared__ float fs[HID];
  __shared__ float logits[NCLASS];
  const int t=threadIdx.x;
  li[t]=leaf[t];
  __syncthreads();
  float m=-INFINITY;
  for(int l=0;l<NLEAVES;l++) m = fmaxf(m, node_h[(size_t)li[l]*HID + t]);
  fs[t]=m;
  __syncthreads();
  const int wave=t>>6, lane=t&63;
  if(wave<NCLASS){
    float p=0.f;
    for(int h=lane;h<HID;h+=64) p += Wout[wave*HID+h]*fs[h];
    for(int off=32; off; off>>=1) p += __shfl_down(p, off);
    if(lane==0) logits[wave]=p+bout[wave];
  }
  __syncthreads();
  if(t==0){
    float mx = fmaxf(fmaxf(logits[0],logits[1]),fmaxf(logits[2],logits[3]));
    float ev[NCLASS]; float es=0.f;
    #pragma unroll
    for(int c=0;c<NCLASS;c++){ ev[c]=expf(logits[c]-mx); es+=ev[c]; }
    float loss=0.f;
    #pragma unroll
    for(int c=0;c<NCLASS;c++){
      float p=ev[c]/es;
      out[c]=p;
      float d=y[c]-p; loss+=d*d;
    }
    out[NCLASS]=loss;
  }
}

// ---------------------------------------------------------------------------
extern "C" void kernel_launch(void* const* d_in, const int* in_sizes, int n_in,
                              void* d_out, int out_size, void* d_ws, size_t ws_size,
                              hipStream_t stream){
  (void)in_sizes; (void)n_in; (void)out_size;
  const float* x_word=(const float*)d_in[0];
  const int*   x_index=(const int*)d_in[1];
  const int*   parent =(const int*)d_in[2];
  const int*   leaf   =(const int*)d_in[3];
  const float* y      =(const float*)d_in[4];
  const float* E      =(const float*)d_in[5];
  const float* W_z=(const float*)d_in[6];  const float* U_z=(const float*)d_in[7];  const float* b_z=(const float*)d_in[8];
  const float* W_r=(const float*)d_in[9];  const float* U_r=(const float*)d_in[10]; const float* b_r=(const float*)d_in[11];
  const float* W_h=(const float*)d_in[12]; const float* U_h=(const float*)d_in[13]; const float* b_h=(const float*)d_in[14];
  const float* W_out=(const float*)d_in[15]; const float* b_out=(const float*)d_in[16];

  size_t off=0;
  char* wsb=(char*)d_ws;
  auto alloc=[&](size_t b)->void*{ void* p=wsb+off; off=(off+b+255)&~(size_t)255; return p; };
  int*  meta   = (int*)  alloc(256);
  int*  lstart = (int*)  alloc((N_NODES+1)*sizeof(int));
  int*  order  = (int*)  alloc(N_NODES*sizeof(int));
  float* node_h= (float*)alloc((size_t)(N_NODES+1)*HID*sizeof(float));
  u16*  xeb    = (u16*)  alloc((size_t)N_NODES*HID*sizeof(u16));
  float* wz    = (float*)alloc((size_t)N_NODES*HID*sizeof(float));
  float* wr    = (float*)alloc((size_t)N_NODES*HID*sizeof(float));
  float* wh    = (float*)alloc((size_t)N_NODES*HID*sizeof(float));
  u16*  Wzb    = (u16*)  alloc((size_t)HID*HID*sizeof(u16));
  u16*  Wrb    = (u16*)  alloc((size_t)HID*HID*sizeof(u16));
  u16*  Whb    = (u16*)  alloc((size_t)HID*HID*sizeof(u16));
  u16*  Uzb    = (u16*)  alloc((size_t)HID*HID*sizeof(u16));
  u16*  Urb    = (u16*)  alloc((size_t)HID*HID*sizeof(u16));
  u16*  Uhb    = (u16*)  alloc((size_t)HID*HID*sizeof(u16));
  float* ET    = (float*)(wsb+off);
  const size_t need_ET = off + (size_t)VOCAB*HID*sizeof(float);
  const bool useET = (ws_size >= need_ET);

  k_levels<<<1,1024,0,stream>>>(parent, meta, lstart, order, node_h);
  k_prep<<<dim3(1024,6),256,0,stream>>>(W_z,W_r,W_h,U_z,U_r,U_h, Wzb,Wrb,Whb,Uzb,Urb,Uhb);
  if(useET){
    k_transpose<<<dim3((VOCAB+31)/32, HID/32),256,0,stream>>>(E, ET);
    k_xe<<<N_NODES,256,0,stream>>>(ET, x_word, x_index, xeb);
  }else{
    k_xe_noET<<<N_NODES,256,0,stream>>>(E, x_word, x_index, xeb);
  }
  k_gemm_in<<<dim3(HID/64, N_NODES/64, 3),256,0,stream>>>(xeb, Wzb,Wrb,Whb, b_z,b_r,b_h, wz,wr,wh);
  for(int lev=0; lev<MAXLEV; ++lev){
    k_lvlA<<<dim3(HID/32, 24, 2),256,0,stream>>>(node_h, Uzb,Urb, wz,wr, parent, lstart, order, lev);
    k_lvlC<<<dim3(HID/32, 24),256,0,stream>>>(node_h, Uhb, wz,wr,wh, parent, lstart, order, lev);
  }
  k_final<<<1,1024,0,stream>>>(node_h, leaf, W_out, b_out, y, (float*)d_out);
}

// Round 17
// 956.505 us; speedup vs baseline: 8.0982x; 1.1921x over previous
//
#include <hip/hip_runtime.h>
#include <hip/hip_bf16.h>
#include <math.h>

#define N_NODES 4096
#define WPN 32
#define HID 1024
#define VOCAB 30000
#define NCLASS 4
#define NLEAVES 1024
#define MAXLEV 40
#define LMB 64                 // leaf-max blocks
#define LPB (NLEAVES/LMB)      // leaves per block

typedef unsigned int u32;
typedef unsigned short u16;
typedef __attribute__((ext_vector_type(8))) short short8v;
typedef __attribute__((ext_vector_type(4))) float f32x4;

__device__ __forceinline__ float sigmf(float x){ return 1.f/(1.f+expf(-x)); }
__device__ __forceinline__ u16 f2bf16(float f){
  u32 x=__float_as_uint(f);
  return (u16)((x + 0x7fffu + ((x>>16)&1u))>>16);
}

// ---------------------------------------------------------------------------
// Level schedule (unchanged).
// ---------------------------------------------------------------------------
__global__ __launch_bounds__(1024) void k_levels(const int* __restrict__ parent,
                                                 int* __restrict__ meta,
                                                 int* __restrict__ lstart,
                                                 int* __restrict__ order,
                                                 float* __restrict__ node_h){
  __shared__ int dep[N_NODES];
  __shared__ int dpt[N_NODES];
  __shared__ int cnt[N_NODES];
  __shared__ int changed, maxd;
  const int t = threadIdx.x;
  for(int i=t;i<N_NODES;i+=1024){ dep[i]=parent[i]-1; dpt[i]=0; cnt[i]=0; }
  if(t==0){ maxd=0; }
  node_h[t]=0.f;
  __syncthreads();
  while(true){
    if(t==0) changed=0;
    __syncthreads();
    bool ch=false;
    for(int i=t;i<N_NODES;i+=1024){
      int d = (dep[i]<0)? 0 : (dpt[dep[i]]+1);
      if(d>dpt[i]){ dpt[i]=d; ch=true; }
    }
    if(ch) changed=1;
    __syncthreads();
    if(!changed) break;
    __syncthreads();
  }
  __syncthreads();
  for(int i=t;i<N_NODES;i+=1024){ atomicAdd(&cnt[dpt[i]],1); atomicMax(&maxd,dpt[i]); }
  __syncthreads();
  int* sc = dep;
  for(int i=t;i<N_NODES;i+=1024) sc[i]=cnt[i];
  __syncthreads();
  for(int off=1; off<N_NODES; off<<=1){
    int v[4];
    #pragma unroll
    for(int u=0;u<4;u++){ int i=t+u*1024; v[u] = (i>=off)? sc[i-off] : 0; }
    __syncthreads();
    #pragma unroll
    for(int u=0;u<4;u++){ int i=t+u*1024; sc[i]+=v[u]; }
    __syncthreads();
  }
  for(int i=t;i<N_NODES;i+=1024) lstart[i+1]=sc[i];
  if(t==0){ lstart[0]=0; meta[0]=maxd+1; }
  for(int i=t;i<N_NODES;i+=1024) cnt[i]=sc[i]-cnt[i];
  __syncthreads();
  for(int i=t;i<N_NODES;i+=1024){
    int pos = atomicAdd(&cnt[dpt[i]],1);
    order[pos]=i;
  }
}

// ---------------------------------------------------------------------------
// fp32 -> bf16 one-time: W_z,W_r,W_h,U_z,U_r,U_h. grid (1024,6).
// ---------------------------------------------------------------------------
__global__ __launch_bounds__(256) void k_prep(const float* __restrict__ Wz,
                                              const float* __restrict__ Wr,
                                              const float* __restrict__ Wh,
                                              const float* __restrict__ Uz,
                                              const float* __restrict__ Ur,
                                              const float* __restrict__ Uh,
                                              u16* __restrict__ Wzb, u16* __restrict__ Wrb,
                                              u16* __restrict__ Whb, u16* __restrict__ Uzb,
                                              u16* __restrict__ Urb, u16* __restrict__ Uhb){
  const size_t i = ((size_t)blockIdx.x*256 + threadIdx.x)*4;
  const float* srcs[6]={Wz,Wr,Wh,Uz,Ur,Uh};
  u16* dsts[6]={Wzb,Wrb,Whb,Uzb,Urb,Uhb};
  const float* src = srcs[blockIdx.y];
  u16* dst = dsts[blockIdx.y];
  const float4 v = *(const float4*)(src+i);
  ushort4 o;
  o.x=f2bf16(v.x); o.y=f2bf16(v.y); o.z=f2bf16(v.z); o.w=f2bf16(v.w);
  *(ushort4*)(dst+i) = o;
}

// ---------------------------------------------------------------------------
// E [HID][VOCAB] f32  ->  ET [VOCAB][HID] f32  (tiled transpose)
// ---------------------------------------------------------------------------
__global__ __launch_bounds__(256) void k_transpose(const float* __restrict__ E,
                                                   float* __restrict__ ET){
  __shared__ float tile[32][33];
  const int v0 = blockIdx.x*32, h0 = blockIdx.y*32;
  const int tx = threadIdx.x%32, ty = threadIdx.x/32;
  #pragma unroll
  for(int i=0;i<4;i++){
    int h = h0+ty+8*i, v = v0+tx;
    tile[ty+8*i][tx] = (v<VOCAB)? E[(size_t)h*VOCAB + v] : 0.f;
  }
  __syncthreads();
  #pragma unroll
  for(int i=0;i<4;i++){
    int v = v0+ty+8*i, h = h0+tx;
    if(v<VOCAB) ET[(size_t)v*HID + h] = tile[tx][ty+8*i];
  }
}

// ---------------------------------------------------------------------------
// xe (bf16 out): xeb[n,h] = bf16( sum_l w[n,l] * ET[idx[n,l], h] )
// ---------------------------------------------------------------------------
__global__ __launch_bounds__(256) void k_xe(const float* __restrict__ ET,
                                            const float* __restrict__ xw,
                                            const int* __restrict__ xi,
                                            u16* __restrict__ xeb){
  const int n = blockIdx.x;
  __shared__ float w[WPN]; __shared__ int id[WPN];
  const int t = threadIdx.x;
  if(t<WPN){ w[t]=xw[n*WPN+t]; id[t]=xi[n*WPN+t]; }
  __syncthreads();
  const int h0 = t*4;
  float a0=0,a1=0,a2=0,a3=0;
  for(int l=0;l<WPN;l++){
    const float4 e = *(const float4*)(ET + (size_t)id[l]*HID + h0);
    const float wl = w[l];
    a0 += wl*e.x; a1 += wl*e.y; a2 += wl*e.z; a3 += wl*e.w;
  }
  ushort4 o; o.x=f2bf16(a0); o.y=f2bf16(a1); o.z=f2bf16(a2); o.w=f2bf16(a3);
  *(ushort4*)(xeb + (size_t)n*HID + h0) = o;
}

__global__ __launch_bounds__(256) void k_xe_noET(const float* __restrict__ E,
                                                 const float* __restrict__ xw,
                                                 const int* __restrict__ xi,
                                                 u16* __restrict__ xeb){
  const int n = blockIdx.x;
  __shared__ float w[WPN]; __shared__ int id[WPN];
  const int t = threadIdx.x;
  if(t<WPN){ w[t]=xw[n*WPN+t]; id[t]=xi[n*WPN+t]; }
  __syncthreads();
  const int h0 = t*4;
  float acc[4]={0,0,0,0};
  for(int l=0;l<WPN;l++){
    const float wl=w[l]; const int ix=id[l];
    #pragma unroll
    for(int j=0;j<4;j++) acc[j] += wl*E[(size_t)(h0+j)*VOCAB + ix];
  }
  ushort4 o; o.x=f2bf16(acc[0]); o.y=f2bf16(acc[1]); o.z=f2bf16(acc[2]); o.w=f2bf16(acc[3]);
  *(ushort4*)(xeb + (size_t)n*HID + h0) = o;
}

// ---------------------------------------------------------------------------
// MFMA input projections (unchanged from v16).
// ---------------------------------------------------------------------------
__global__ __launch_bounds__(256) void k_gemm_in(const u16* __restrict__ xeb,
  const u16* __restrict__ W0,const u16* __restrict__ W1,const u16* __restrict__ W2,
  const float* __restrict__ b0,const float* __restrict__ b1,const float* __restrict__ b2,
  float* __restrict__ o0p,float* __restrict__ o1p,float* __restrict__ o2p){
  const int g=blockIdx.z;
  const u16* W    = (g==0)?W0:((g==1)?W1:W2);
  const float* bi = (g==0)?b0:((g==1)?b1:b2);
  float* out      = (g==0)?o0p:((g==1)?o1p:o2p);
  const int m0=blockIdx.x<<6;
  const int n0=blockIdx.y<<6;
  __shared__ __align__(16) u16 As[64*40];
  __shared__ __align__(16) u16 Bs[64*40];
  const int t=threadIdx.x, lane=t&63, w=t>>6;
  const int srow=t>>2, sk8=(t&3)<<3;
  const u16* ap = W   + (size_t)(m0+srow)*HID + sk8;
  const u16* bp = xeb + (size_t)(n0+srow)*HID + sk8;
  const int qr=w&1, qc=w>>1;
  f32x4 acc[2][2]={};
  const int abase = (qr<<5)*40, bbase = (qc<<5)*40;
  const int lrow=(lane&15)*40, lk=((lane>>4)<<3);
  for(int k0=0;k0<HID;k0+=32){
    *(short8v*)&As[srow*40 + sk8] = *(const short8v*)(ap + k0);
    *(short8v*)&Bs[srow*40 + sk8] = *(const short8v*)(bp + k0);
    __syncthreads();
    short8v af0 = *(const short8v*)&As[abase + lrow + lk];
    short8v af1 = *(const short8v*)&As[abase + 16*40 + lrow + lk];
    short8v bf0 = *(const short8v*)&Bs[bbase + lrow + lk];
    short8v bf1 = *(const short8v*)&Bs[bbase + 16*40 + lrow + lk];
    acc[0][0]=__builtin_amdgcn_mfma_f32_16x16x32_bf16(af0,bf0,acc[0][0],0,0,0);
    acc[0][1]=__builtin_amdgcn_mfma_f32_16x16x32_bf16(af0,bf1,acc[0][1],0,0,0);
    acc[1][0]=__builtin_amdgcn_mfma_f32_16x16x32_bf16(af1,bf0,acc[1][0],0,0,0);
    acc[1][1]=__builtin_amdgcn_mfma_f32_16x16x32_bf16(af1,bf1,acc[1][1],0,0,0);
    __syncthreads();
  }
  #pragma unroll
  for(int fi=0;fi<2;fi++){
    const int o = m0 + (qr<<5) + fi*16 + ((lane>>4)<<2);
    const float4 bb = *(const float4*)(bi + o);
    #pragma unroll
    for(int fj=0;fj<2;fj++){
      const int n = n0 + (qc<<5) + fj*16 + (lane&15);
      float4 r4 = make_float4(acc[fi][fj][0]+bb.x, acc[fi][fj][1]+bb.y,
                              acc[fi][fj][2]+bb.z, acc[fi][fj][3]+bb.w);
      *(float4*)(out + (size_t)n*HID + o) = r4;
    }
  }
}

// ---------------------------------------------------------------------------
// Level MFMA kernels (unchanged — proven absmax 0.0).
// ---------------------------------------------------------------------------
__global__ void k_lvlA(const float* __restrict__ node_h,
                       const u16* __restrict__ Uzb, const u16* __restrict__ Urb,
                       float* __restrict__ wz, float* __restrict__ wr,
                       const int* __restrict__ parent,
                       const int* __restrict__ lstart, const int* __restrict__ order,
                       int lev){
  const int s = lstart[lev];
  const int L = lstart[lev+1] - s;
  const int j0 = blockIdx.y<<5;
  if(j0 >= L) return;
  const int m0 = blockIdx.x<<5;
  const int gate = blockIdx.z;
  const u16* U = gate? Urb : Uzb;
  __shared__ __align__(16) u16 As[32*40];
  __shared__ __align__(16) u16 Bs[32*40];
  __shared__ int nds[32], pds[32];
  const int t=threadIdx.x, lane=t&63, w=t>>6;
  if(t<32){
    const int j=j0+t;
    const int n=(j<L)? order[s+j] : 0;
    nds[t]=n; pds[t]=(j<L)? parent[n] : 0;
  }
  __syncthreads();
  const int srow=t>>3, sk4=(t&7)<<2;
  const float* bp = node_h + (size_t)pds[srow]*HID;
  const u16*   ap = U + (size_t)(m0+srow)*HID;
  const int qr=w&1, qc=w>>1;
  f32x4 acc = {0.f,0.f,0.f,0.f};
  const int afo = (16*qr + (lane&15))*40 + ((lane>>4)<<3);
  const int bfo = (16*qc + (lane&15))*40 + ((lane>>4)<<3);
  for(int k0=0;k0<HID;k0+=32){
    *(ushort4*)&As[srow*40 + sk4] = *(const ushort4*)(ap + k0 + sk4);
    const float4 bv = *(const float4*)(bp + k0 + sk4);
    ushort4 bw;
    bw.x=f2bf16(bv.x); bw.y=f2bf16(bv.y); bw.z=f2bf16(bv.z); bw.w=f2bf16(bv.w);
    *(ushort4*)&Bs[srow*40 + sk4] = bw;
    __syncthreads();
    const short8v af = *(const short8v*)&As[afo];
    const short8v bf = *(const short8v*)&Bs[bfo];
    acc = __builtin_amdgcn_mfma_f32_16x16x32_bf16(af, bf, acc, 0,0,0);
    __syncthreads();
  }
  const int jl = 16*qc + (lane&15);
  if(j0 + jl < L){
    const int n = nds[jl], p = pds[jl];
    const int mb = m0 + 16*qr + ((lane>>4)<<2);
    if(gate==0){
      float4 wv = *(float4*)(wz + (size_t)n*HID + mb);
      wv.x=sigmf(wv.x+acc[0]); wv.y=sigmf(wv.y+acc[1]);
      wv.z=sigmf(wv.z+acc[2]); wv.w=sigmf(wv.w+acc[3]);
      *(float4*)(wz + (size_t)n*HID + mb) = wv;
    }else{
      float4 wv = *(float4*)(wr + (size_t)n*HID + mb);
      const float4 ph = *(const float4*)(node_h + (size_t)p*HID + mb);
      wv.x=sigmf(wv.x+acc[0])*ph.x; wv.y=sigmf(wv.y+acc[1])*ph.y;
      wv.z=sigmf(wv.z+acc[2])*ph.z; wv.w=sigmf(wv.w+acc[3])*ph.w;
      *(float4*)(wr + (size_t)n*HID + mb) = wv;
    }
  }
}

__global__ void k_lvlC(float* __restrict__ node_h,
                       const u16* __restrict__ Uhb,
                       const float* __restrict__ wz, const float* __restrict__ wr,
                       const float* __restrict__ wh,
                       const int* __restrict__ parent,
                       const int* __restrict__ lstart, const int* __restrict__ order,
                       int lev){
  const int s = lstart[lev];
  const int L = lstart[lev+1] - s;
  const int j0 = blockIdx.y<<5;
  if(j0 >= L) return;
  const int m0 = blockIdx.x<<5;
  __shared__ __align__(16) u16 As[32*40];
  __shared__ __align__(16) u16 Bs[32*40];
  __shared__ int nds[32], pds[32];
  const int t=threadIdx.x, lane=t&63, w=t>>6;
  if(t<32){
    const int j=j0+t;
    const int n=(j<L)? order[s+j] : 0;
    nds[t]=n; pds[t]=(j<L)? parent[n] : 0;
  }
  __syncthreads();
  const int srow=t>>3, sk4=(t&7)<<2;
  const float* bp = wr + (size_t)nds[srow]*HID;
  const u16*   ap = Uhb + (size_t)(m0+srow)*HID;
  const int qr=w&1, qc=w>>1;
  f32x4 acc = {0.f,0.f,0.f,0.f};
  const int afo = (16*qr + (lane&15))*40 + ((lane>>4)<<3);
  const int bfo = (16*qc + (lane&15))*40 + ((lane>>4)<<3);
  for(int k0=0;k0<HID;k0+=32){
    *(ushort4*)&As[srow*40 + sk4] = *(const ushort4*)(ap + k0 + sk4);
    const float4 bv = *(const float4*)(bp + k0 + sk4);
    ushort4 bw;
    bw.x=f2bf16(bv.x); bw.y=f2bf16(bv.y); bw.z=f2bf16(bv.z); bw.w=f2bf16(bv.w);
    *(ushort4*)&Bs[srow*40 + sk4] = bw;
    __syncthreads();
    const short8v af = *(const short8v*)&As[afo];
    const short8v bf = *(const short8v*)&Bs[bfo];
    acc = __builtin_amdgcn_mfma_f32_16x16x32_bf16(af, bf, acc, 0,0,0);
    __syncthreads();
  }
  const int jl = 16*qc + (lane&15);
  if(j0 + jl < L){
    const int n = nds[jl], p = pds[jl];
    const int mb = m0 + 16*qr + ((lane>>4)<<2);
    const float4 whv = *(const float4*)(wh + (size_t)n*HID + mb);
    const float4 z4  = *(const float4*)(wz + (size_t)n*HID + mb);
    const float4 ph  = *(const float4*)(node_h + (size_t)p*HID + mb);
    float4 hn;
    hn.x = z4.x*ph.x + (1.f-z4.x)*tanhf(whv.x+acc[0]);
    hn.y = z4.y*ph.y + (1.f-z4.y)*tanhf(whv.y+acc[1]);
    hn.z = z4.z*ph.z + (1.f-z4.z)*tanhf(whv.z+acc[2]);
    hn.w = z4.w*ph.w + (1.f-z4.w)*tanhf(whv.w+acc[3]);
    *(float4*)(node_h + (size_t)(n+1)*HID + mb) = hn;
  }
}

// ---------------------------------------------------------------------------
// v17 leaf max: stage 1 — 64 blocks x 16 leaves each, parallel 4MB read.
// ---------------------------------------------------------------------------
__global__ __launch_bounds__(1024) void k_leafmax(const float* __restrict__ node_h,
                                                  const int* __restrict__ leaf,
                                                  float* __restrict__ partial){
  const int b = blockIdx.x, t = threadIdx.x;
  __shared__ int li[LPB];
  if(t<LPB) li[t] = leaf[b*LPB + t];
  __syncthreads();
  float m = -INFINITY;
  #pragma unroll
  for(int l=0;l<LPB;l++) m = fmaxf(m, node_h[(size_t)li[l]*HID + t]);
  partial[(size_t)b*HID + t] = m;
}

// stage 2 — reduce partials + logits + softmax + loss.
__global__ __launch_bounds__(1024) void k_final2(const float* __restrict__ partial,
                                                 const float* __restrict__ Wout,
                                                 const float* __restrict__ bout,
                                                 const float* __restrict__ y,
                                                 float* __restrict__ out){
  __shared__ float fs[HID];
  __shared__ float logits[NCLASS];
  const int t=threadIdx.x;
  float m=-INFINITY;
  for(int b=0;b<LMB;b++) m = fmaxf(m, partial[(size_t)b*HID + t]);
  fs[t]=m;
  __syncthreads();
  const int wave=t>>6, lane=t&63;
  if(wave<NCLASS){
    float p=0.f;
    for(int h=lane;h<HID;h+=64) p += Wout[wave*HID+h]*fs[h];
    for(int off=32; off; off>>=1) p += __shfl_down(p, off);
    if(lane==0) logits[wave]=p+bout[wave];
  }
  __syncthreads();
  if(t==0){
    float mx = fmaxf(fmaxf(logits[0],logits[1]),fmaxf(logits[2],logits[3]));
    float ev[NCLASS]; float es=0.f;
    #pragma unroll
    for(int c=0;c<NCLASS;c++){ ev[c]=expf(logits[c]-mx); es+=ev[c]; }
    float loss=0.f;
    #pragma unroll
    for(int c=0;c<NCLASS;c++){
      float p=ev[c]/es;
      out[c]=p;
      float d=y[c]-p; loss+=d*d;
    }
    out[NCLASS]=loss;
  }
}

// ---------------------------------------------------------------------------
extern "C" void kernel_launch(void* const* d_in, const int* in_sizes, int n_in,
                              void* d_out, int out_size, void* d_ws, size_t ws_size,
                              hipStream_t stream){
  (void)in_sizes; (void)n_in; (void)out_size;
  const float* x_word=(const float*)d_in[0];
  const int*   x_index=(const int*)d_in[1];
  const int*   parent =(const int*)d_in[2];
  const int*   leaf   =(const int*)d_in[3];
  const float* y      =(const float*)d_in[4];
  const float* E      =(const float*)d_in[5];
  const float* W_z=(const float*)d_in[6];  const float* U_z=(const float*)d_in[7];  const float* b_z=(const float*)d_in[8];
  const float* W_r=(const float*)d_in[9];  const float* U_r=(const float*)d_in[10]; const float* b_r=(const float*)d_in[11];
  const float* W_h=(const float*)d_in[12]; const float* U_h=(const float*)d_in[13]; const float* b_h=(const float*)d_in[14];
  const float* W_out=(const float*)d_in[15]; const float* b_out=(const float*)d_in[16];

  size_t off=0;
  char* wsb=(char*)d_ws;
  auto alloc=[&](size_t b)->void*{ void* p=wsb+off; off=(off+b+255)&~(size_t)255; return p; };
  int*  meta   = (int*)  alloc(256);
  int*  lstart = (int*)  alloc((N_NODES+1)*sizeof(int));
  int*  order  = (int*)  alloc(N_NODES*sizeof(int));
  float* node_h= (float*)alloc((size_t)(N_NODES+1)*HID*sizeof(float));
  u16*  xeb    = (u16*)  alloc((size_t)N_NODES*HID*sizeof(u16));
  float* wz    = (float*)alloc((size_t)N_NODES*HID*sizeof(float));
  float* wr    = (float*)alloc((size_t)N_NODES*HID*sizeof(float));
  float* wh    = (float*)alloc((size_t)N_NODES*HID*sizeof(float));
  float* part  = (float*)alloc((size_t)LMB*HID*sizeof(float));
  u16*  Wzb    = (u16*)  alloc((size_t)HID*HID*sizeof(u16));
  u16*  Wrb    = (u16*)  alloc((size_t)HID*HID*sizeof(u16));
  u16*  Whb    = (u16*)  alloc((size_t)HID*HID*sizeof(u16));
  u16*  Uzb    = (u16*)  alloc((size_t)HID*HID*sizeof(u16));
  u16*  Urb    = (u16*)  alloc((size_t)HID*HID*sizeof(u16));
  u16*  Uhb    = (u16*)  alloc((size_t)HID*HID*sizeof(u16));
  float* ET    = (float*)(wsb+off);
  const size_t need_ET = off + (size_t)VOCAB*HID*sizeof(float);
  const bool useET = (ws_size >= need_ET);

  k_levels<<<1,1024,0,stream>>>(parent, meta, lstart, order, node_h);
  k_prep<<<dim3(1024,6),256,0,stream>>>(W_z,W_r,W_h,U_z,U_r,U_h, Wzb,Wrb,Whb,Uzb,Urb,Uhb);
  if(useET){
    k_transpose<<<dim3((VOCAB+31)/32, HID/32),256,0,stream>>>(E, ET);
    k_xe<<<N_NODES,256,0,stream>>>(ET, x_word, x_index, xeb);
  }else{
    k_xe_noET<<<N_NODES,256,0,stream>>>(E, x_word, x_index, xeb);
  }
  k_gemm_in<<<dim3(HID/64, N_NODES/64, 3),256,0,stream>>>(xeb, Wzb,Wrb,Whb, b_z,b_r,b_h, wz,wr,wh);
  for(int lev=0; lev<MAXLEV; ++lev){
    k_lvlA<<<dim3(HID/32, 24, 2),256,0,stream>>>(node_h, Uzb,Urb, wz,wr, parent, lstart, order, lev);
    k_lvlC<<<dim3(HID/32, 24),256,0,stream>>>(node_h, Uhb, wz,wr,wh, parent, lstart, order, lev);
  }
  k_leafmax<<<LMB,1024,0,stream>>>(node_h, leaf, part);
  k_final2<<<1,1024,0,stream>>>(part, W_out, b_out, y, (float*)d_out);
}

// Round 18
// 663.380 us; speedup vs baseline: 11.6766x; 1.4419x over previous
//
#include <hip/hip_runtime.h>
#include <hip/hip_bf16.h>
#include <math.h>

#define N_NODES 4096
#define WPN 32
#define HID 1024
#define VOCAB 30000
#define NCLASS 4
#define NLEAVES 1024
#define MAXLEV 40
#define LMB 64
#define LPB (NLEAVES/LMB)

typedef unsigned int u32;
typedef unsigned short u16;
typedef __attribute__((ext_vector_type(8))) short short8v;
typedef __attribute__((ext_vector_type(4))) float f32x4;

__device__ __forceinline__ float sigmf(float x){ return 1.f/(1.f+expf(-x)); }
__device__ __forceinline__ u16 f2bf16(float f){
  u32 x=__float_as_uint(f);
  return (u16)((x + 0x7fffu + ((x>>16)&1u))>>16);
}
__device__ __forceinline__ float bfu(u16 v){ return __uint_as_float(((u32)v)<<16); }

// ---------------------------------------------------------------------------
// Level schedule (unchanged).
// ---------------------------------------------------------------------------
__global__ __launch_bounds__(1024) void k_levels(const int* __restrict__ parent,
                                                 int* __restrict__ meta,
                                                 int* __restrict__ lstart,
                                                 int* __restrict__ order,
                                                 float* __restrict__ node_h){
  __shared__ int dep[N_NODES];
  __shared__ int dpt[N_NODES];
  __shared__ int cnt[N_NODES];
  __shared__ int changed, maxd;
  const int t = threadIdx.x;
  for(int i=t;i<N_NODES;i+=1024){ dep[i]=parent[i]-1; dpt[i]=0; cnt[i]=0; }
  if(t==0){ maxd=0; }
  node_h[t]=0.f;
  __syncthreads();
  while(true){
    if(t==0) changed=0;
    __syncthreads();
    bool ch=false;
    for(int i=t;i<N_NODES;i+=1024){
      int d = (dep[i]<0)? 0 : (dpt[dep[i]]+1);
      if(d>dpt[i]){ dpt[i]=d; ch=true; }
    }
    if(ch) changed=1;
    __syncthreads();
    if(!changed) break;
    __syncthreads();
  }
  __syncthreads();
  for(int i=t;i<N_NODES;i+=1024){ atomicAdd(&cnt[dpt[i]],1); atomicMax(&maxd,dpt[i]); }
  __syncthreads();
  int* sc = dep;
  for(int i=t;i<N_NODES;i+=1024) sc[i]=cnt[i];
  __syncthreads();
  for(int off=1; off<N_NODES; off<<=1){
    int v[4];
    #pragma unroll
    for(int u=0;u<4;u++){ int i=t+u*1024; v[u] = (i>=off)? sc[i-off] : 0; }
    __syncthreads();
    #pragma unroll
    for(int u=0;u<4;u++){ int i=t+u*1024; sc[i]+=v[u]; }
    __syncthreads();
  }
  for(int i=t;i<N_NODES;i+=1024) lstart[i+1]=sc[i];
  if(t==0){ lstart[0]=0; meta[0]=maxd+1; }
  for(int i=t;i<N_NODES;i+=1024) cnt[i]=sc[i]-cnt[i];
  __syncthreads();
  for(int i=t;i<N_NODES;i+=1024){
    int pos = atomicAdd(&cnt[dpt[i]],1);
    order[pos]=i;
  }
}

// ---------------------------------------------------------------------------
// fp32 -> bf16 one-time: W_z,W_r,W_h,U_z,U_r,U_h. grid (1024,6).
// ---------------------------------------------------------------------------
__global__ __launch_bounds__(256) void k_prep(const float* __restrict__ Wz,
                                              const float* __restrict__ Wr,
                                              const float* __restrict__ Wh,
                                              const float* __restrict__ Uz,
                                              const float* __restrict__ Ur,
                                              const float* __restrict__ Uh,
                                              u16* __restrict__ Wzb, u16* __restrict__ Wrb,
                                              u16* __restrict__ Whb, u16* __restrict__ Uzb,
                                              u16* __restrict__ Urb, u16* __restrict__ Uhb){
  const size_t i = ((size_t)blockIdx.x*256 + threadIdx.x)*4;
  const float* srcs[6]={Wz,Wr,Wh,Uz,Ur,Uh};
  u16* dsts[6]={Wzb,Wrb,Whb,Uzb,Urb,Uhb};
  const float* src = srcs[blockIdx.y];
  u16* dst = dsts[blockIdx.y];
  const float4 v = *(const float4*)(src+i);
  ushort4 o;
  o.x=f2bf16(v.x); o.y=f2bf16(v.y); o.z=f2bf16(v.z); o.w=f2bf16(v.w);
  *(ushort4*)(dst+i) = o;
}

// ---------------------------------------------------------------------------
// E [HID][VOCAB] f32  ->  ETb [VOCAB][HID] bf16  (tiled transpose, bf16 out)
// ---------------------------------------------------------------------------
__global__ __launch_bounds__(256) void k_transpose(const float* __restrict__ E,
                                                   u16* __restrict__ ETb){
  __shared__ float tile[32][33];
  const int v0 = blockIdx.x*32, h0 = blockIdx.y*32;
  const int tx = threadIdx.x%32, ty = threadIdx.x/32;
  #pragma unroll
  for(int i=0;i<4;i++){
    int h = h0+ty+8*i, v = v0+tx;
    tile[ty+8*i][tx] = (v<VOCAB)? E[(size_t)h*VOCAB + v] : 0.f;
  }
  __syncthreads();
  #pragma unroll
  for(int i=0;i<4;i++){
    int v = v0+ty+8*i, h = h0+tx;
    if(v<VOCAB) ETb[(size_t)v*HID + h] = f2bf16(tile[tx][ty+8*i]);
  }
}

// ---------------------------------------------------------------------------
// xe (bf16 in/out): xeb[n,h] = bf16( sum_l w[n,l] * ETb[idx[n,l], h] )
// ---------------------------------------------------------------------------
__global__ __launch_bounds__(256) void k_xe(const u16* __restrict__ ETb,
                                            const float* __restrict__ xw,
                                            const int* __restrict__ xi,
                                            u16* __restrict__ xeb){
  const int n = blockIdx.x;
  __shared__ float w[WPN]; __shared__ int id[WPN];
  const int t = threadIdx.x;
  if(t<WPN){ w[t]=xw[n*WPN+t]; id[t]=xi[n*WPN+t]; }
  __syncthreads();
  const int h0 = t*4;
  float a0=0,a1=0,a2=0,a3=0;
  for(int l=0;l<WPN;l++){
    const ushort4 e = *(const ushort4*)(ETb + (size_t)id[l]*HID + h0);
    const float wl = w[l];
    a0 += wl*bfu(e.x); a1 += wl*bfu(e.y); a2 += wl*bfu(e.z); a3 += wl*bfu(e.w);
  }
  ushort4 o; o.x=f2bf16(a0); o.y=f2bf16(a1); o.z=f2bf16(a2); o.w=f2bf16(a3);
  *(ushort4*)(xeb + (size_t)n*HID + h0) = o;
}

__global__ __launch_bounds__(256) void k_xe_noET(const float* __restrict__ E,
                                                 const float* __restrict__ xw,
                                                 const int* __restrict__ xi,
                                                 u16* __restrict__ xeb){
  const int n = blockIdx.x;
  __shared__ float w[WPN]; __shared__ int id[WPN];
  const int t = threadIdx.x;
  if(t<WPN){ w[t]=xw[n*WPN+t]; id[t]=xi[n*WPN+t]; }
  __syncthreads();
  const int h0 = t*4;
  float acc[4]={0,0,0,0};
  for(int l=0;l<WPN;l++){
    const float wl=w[l]; const int ix=id[l];
    #pragma unroll
    for(int j=0;j<4;j++) acc[j] += wl*E[(size_t)(h0+j)*VOCAB + ix];
  }
  ushort4 o; o.x=f2bf16(acc[0]); o.y=f2bf16(acc[1]); o.z=f2bf16(acc[2]); o.w=f2bf16(acc[3]);
  *(ushort4*)(xeb + (size_t)n*HID + h0) = o;
}

// ---------------------------------------------------------------------------
// MFMA input projections (unchanged from v16).
// ---------------------------------------------------------------------------
__global__ __launch_bounds__(256) void k_gemm_in(const u16* __restrict__ xeb,
  const u16* __restrict__ W0,const u16* __restrict__ W1,const u16* __restrict__ W2,
  const float* __restrict__ b0,const float* __restrict__ b1,const float* __restrict__ b2,
  float* __restrict__ o0p,float* __restrict__ o1p,float* __restrict__ o2p){
  const int g=blockIdx.z;
  const u16* W    = (g==0)?W0:((g==1)?W1:W2);
  const float* bi = (g==0)?b0:((g==1)?b1:b2);
  float* out      = (g==0)?o0p:((g==1)?o1p:o2p);
  const int m0=blockIdx.x<<6;
  const int n0=blockIdx.y<<6;
  __shared__ __align__(16) u16 As[64*40];
  __shared__ __align__(16) u16 Bs[64*40];
  const int t=threadIdx.x, lane=t&63, w=t>>6;
  const int srow=t>>2, sk8=(t&3)<<3;
  const u16* ap = W   + (size_t)(m0+srow)*HID + sk8;
  const u16* bp = xeb + (size_t)(n0+srow)*HID + sk8;
  const int qr=w&1, qc=w>>1;
  f32x4 acc[2][2]={};
  const int abase = (qr<<5)*40, bbase = (qc<<5)*40;
  const int lrow=(lane&15)*40, lk=((lane>>4)<<3);
  for(int k0=0;k0<HID;k0+=32){
    *(short8v*)&As[srow*40 + sk8] = *(const short8v*)(ap + k0);
    *(short8v*)&Bs[srow*40 + sk8] = *(const short8v*)(bp + k0);
    __syncthreads();
    short8v af0 = *(const short8v*)&As[abase + lrow + lk];
    short8v af1 = *(const short8v*)&As[abase + 16*40 + lrow + lk];
    short8v bf0 = *(const short8v*)&Bs[bbase + lrow + lk];
    short8v bf1 = *(const short8v*)&Bs[bbase + 16*40 + lrow + lk];
    acc[0][0]=__builtin_amdgcn_mfma_f32_16x16x32_bf16(af0,bf0,acc[0][0],0,0,0);
    acc[0][1]=__builtin_amdgcn_mfma_f32_16x16x32_bf16(af0,bf1,acc[0][1],0,0,0);
    acc[1][0]=__builtin_amdgcn_mfma_f32_16x16x32_bf16(af1,bf0,acc[1][0],0,0,0);
    acc[1][1]=__builtin_amdgcn_mfma_f32_16x16x32_bf16(af1,bf1,acc[1][1],0,0,0);
    __syncthreads();
  }
  #pragma unroll
  for(int fi=0;fi<2;fi++){
    const int o = m0 + (qr<<5) + fi*16 + ((lane>>4)<<2);
    const float4 bb = *(const float4*)(bi + o);
    #pragma unroll
    for(int fj=0;fj<2;fj++){
      const int n = n0 + (qc<<5) + fj*16 + (lane&15);
      float4 r4 = make_float4(acc[fi][fj][0]+bb.x, acc[fi][fj][1]+bb.y,
                              acc[fi][fj][2]+bb.z, acc[fi][fj][3]+bb.w);
      *(float4*)(out + (size_t)n*HID + o) = r4;
    }
  }
}

// ---------------------------------------------------------------------------
// v18 level kernels: BK=64 (half the barriers), 2 MFMA/iter, register
// prefetch of next k-chunk issued while MFMAs run. LDS stride 72.
// ---------------------------------------------------------------------------
__global__ void k_lvlA(const float* __restrict__ node_h,
                       const u16* __restrict__ Uzb, const u16* __restrict__ Urb,
                       float* __restrict__ wz, float* __restrict__ wr,
                       const int* __restrict__ parent,
                       const int* __restrict__ lstart, const int* __restrict__ order,
                       int lev){
  const int s = lstart[lev];
  const int L = lstart[lev+1] - s;
  const int j0 = blockIdx.y<<5;
  if(j0 >= L) return;
  const int m0 = blockIdx.x<<5;
  const int gate = blockIdx.z;
  const u16* U = gate? Urb : Uzb;
  __shared__ __align__(16) u16 As[32*72];
  __shared__ __align__(16) u16 Bs[32*72];
  __shared__ int nds[32], pds[32];
  const int t=threadIdx.x, lane=t&63, w=t>>6;
  if(t<32){
    const int j=j0+t;
    const int n=(j<L)? order[s+j] : 0;
    nds[t]=n; pds[t]=(j<L)? parent[n] : 0;
  }
  __syncthreads();
  const int srow=t>>3, sc8=(t&7)<<3;          // row 0..31, 8 elems of 64-k chunk
  const u16*   ap = U + (size_t)(m0+srow)*HID + sc8;
  const float* bp = node_h + (size_t)pds[srow]*HID + sc8;
  short8v aR = *(const short8v*)(ap);
  float4 bR0 = *(const float4*)(bp);
  float4 bR1 = *(const float4*)(bp+4);
  const int qr=w&1, qc=w>>1;
  f32x4 acc = {0.f,0.f,0.f,0.f};
  const int arow=(16*qr+(lane&15))*72, brow=(16*qc+(lane&15))*72;
  const int lk=((lane>>4)<<3);
  for(int k0=0;k0<HID;k0+=64){
    *(short8v*)&As[srow*72+sc8] = aR;
    ushort4 p0,p1;
    p0.x=f2bf16(bR0.x); p0.y=f2bf16(bR0.y); p0.z=f2bf16(bR0.z); p0.w=f2bf16(bR0.w);
    p1.x=f2bf16(bR1.x); p1.y=f2bf16(bR1.y); p1.z=f2bf16(bR1.z); p1.w=f2bf16(bR1.w);
    *(ushort4*)&Bs[srow*72+sc8]   = p0;
    *(ushort4*)&Bs[srow*72+sc8+4] = p1;
    __syncthreads();
    if(k0+64<HID){
      aR  = *(const short8v*)(ap + k0+64);
      bR0 = *(const float4*)(bp + k0+64);
      bR1 = *(const float4*)(bp + k0+68);
    }
    short8v af0 = *(const short8v*)&As[arow + lk];
    short8v bf0 = *(const short8v*)&Bs[brow + lk];
    acc = __builtin_amdgcn_mfma_f32_16x16x32_bf16(af0,bf0,acc,0,0,0);
    short8v af1 = *(const short8v*)&As[arow + 32 + lk];
    short8v bf1 = *(const short8v*)&Bs[brow + 32 + lk];
    acc = __builtin_amdgcn_mfma_f32_16x16x32_bf16(af1,bf1,acc,0,0,0);
    __syncthreads();
  }
  const int jl = 16*qc + (lane&15);
  if(j0 + jl < L){
    const int n = nds[jl], p = pds[jl];
    const int mb = m0 + 16*qr + ((lane>>4)<<2);
    if(gate==0){
      float4 wv = *(float4*)(wz + (size_t)n*HID + mb);
      wv.x=sigmf(wv.x+acc[0]); wv.y=sigmf(wv.y+acc[1]);
      wv.z=sigmf(wv.z+acc[2]); wv.w=sigmf(wv.w+acc[3]);
      *(float4*)(wz + (size_t)n*HID + mb) = wv;
    }else{
      float4 wv = *(float4*)(wr + (size_t)n*HID + mb);
      const float4 ph = *(const float4*)(node_h + (size_t)p*HID + mb);
      wv.x=sigmf(wv.x+acc[0])*ph.x; wv.y=sigmf(wv.y+acc[1])*ph.y;
      wv.z=sigmf(wv.z+acc[2])*ph.z; wv.w=sigmf(wv.w+acc[3])*ph.w;
      *(float4*)(wr + (size_t)n*HID + mb) = wv;
    }
  }
}

__global__ void k_lvlC(float* __restrict__ node_h,
                       const u16* __restrict__ Uhb,
                       const float* __restrict__ wz, const float* __restrict__ wr,
                       const float* __restrict__ wh,
                       const int* __restrict__ parent,
                       const int* __restrict__ lstart, const int* __restrict__ order,
                       int lev){
  const int s = lstart[lev];
  const int L = lstart[lev+1] - s;
  const int j0 = blockIdx.y<<5;
  if(j0 >= L) return;
  const int m0 = blockIdx.x<<5;
  __shared__ __align__(16) u16 As[32*72];
  __shared__ __align__(16) u16 Bs[32*72];
  __shared__ int nds[32], pds[32];
  const int t=threadIdx.x, lane=t&63, w=t>>6;
  if(t<32){
    const int j=j0+t;
    const int n=(j<L)? order[s+j] : 0;
    nds[t]=n; pds[t]=(j<L)? parent[n] : 0;
  }
  __syncthreads();
  const int srow=t>>3, sc8=(t&7)<<3;
  const u16*   ap = Uhb + (size_t)(m0+srow)*HID + sc8;
  const float* bp = wr + (size_t)nds[srow]*HID + sc8;
  short8v aR = *(const short8v*)(ap);
  float4 bR0 = *(const float4*)(bp);
  float4 bR1 = *(const float4*)(bp+4);
  const int qr=w&1, qc=w>>1;
  f32x4 acc = {0.f,0.f,0.f,0.f};
  const int arow=(16*qr+(lane&15))*72, brow=(16*qc+(lane&15))*72;
  const int lk=((lane>>4)<<3);
  for(int k0=0;k0<HID;k0+=64){
    *(short8v*)&As[srow*72+sc8] = aR;
    ushort4 p0,p1;
    p0.x=f2bf16(bR0.x); p0.y=f2bf16(bR0.y); p0.z=f2bf16(bR0.z); p0.w=f2bf16(bR0.w);
    p1.x=f2bf16(bR1.x); p1.y=f2bf16(bR1.y); p1.z=f2bf16(bR1.z); p1.w=f2bf16(bR1.w);
    *(ushort4*)&Bs[srow*72+sc8]   = p0;
    *(ushort4*)&Bs[srow*72+sc8+4] = p1;
    __syncthreads();
    if(k0+64<HID){
      aR  = *(const short8v*)(ap + k0+64);
      bR0 = *(const float4*)(bp + k0+64);
      bR1 = *(const float4*)(bp + k0+68);
    }
    short8v af0 = *(const short8v*)&As[arow + lk];
    short8v bf0 = *(const short8v*)&Bs[brow + lk];
    acc = __builtin_amdgcn_mfma_f32_16x16x32_bf16(af0,bf0,acc,0,0,0);
    short8v af1 = *(const short8v*)&As[arow + 32 + lk];
    short8v bf1 = *(const short8v*)&Bs[brow + 32 + lk];
    acc = __builtin_amdgcn_mfma_f32_16x16x32_bf16(af1,bf1,acc,0,0,0);
    __syncthreads();
  }
  const int jl = 16*qc + (lane&15);
  if(j0 + jl < L){
    const int n = nds[jl], p = pds[jl];
    const int mb = m0 + 16*qr + ((lane>>4)<<2);
    const float4 whv = *(const float4*)(wh + (size_t)n*HID + mb);
    const float4 z4  = *(const float4*)(wz + (size_t)n*HID + mb);
    const float4 ph  = *(const float4*)(node_h + (size_t)p*HID + mb);
    float4 hn;
    hn.x = z4.x*ph.x + (1.f-z4.x)*tanhf(whv.x+acc[0]);
    hn.y = z4.y*ph.y + (1.f-z4.y)*tanhf(whv.y+acc[1]);
    hn.z = z4.z*ph.z + (1.f-z4.z)*tanhf(whv.z+acc[2]);
    hn.w = z4.w*ph.w + (1.f-z4.w)*tanhf(whv.w+acc[3]);
    *(float4*)(node_h + (size_t)(n+1)*HID + mb) = hn;
  }
}

// ---------------------------------------------------------------------------
// Leaf max two-stage (unchanged from v17).
// ---------------------------------------------------------------------------
__global__ __launch_bounds__(1024) void k_leafmax(const float* __restrict__ node_h,
                                                  const int* __restrict__ leaf,
                                                  float* __restrict__ partial){
  const int b = blockIdx.x, t = threadIdx.x;
  __shared__ int li[LPB];
  if(t<LPB) li[t] = leaf[b*LPB + t];
  __syncthreads();
  float m = -INFINITY;
  #pragma unroll
  for(int l=0;l<LPB;l++) m = fmaxf(m, node_h[(size_t)li[l]*HID + t]);
  partial[(size_t)b*HID + t] = m;
}

__global__ __launch_bounds__(1024) void k_final2(const float* __restrict__ partial,
                                                 const float* __restrict__ Wout,
                                                 const float* __restrict__ bout,
                                                 const float* __restrict__ y,
                                                 float* __restrict__ out){
  __shared__ float fs[HID];
  __shared__ float logits[NCLASS];
  const int t=threadIdx.x;
  float m=-INFINITY;
  for(int b=0;b<LMB;b++) m = fmaxf(m, partial[(size_t)b*HID + t]);
  fs[t]=m;
  __syncthreads();
  const int wave=t>>6, lane=t&63;
  if(wave<NCLASS){
    float p=0.f;
    for(int h=lane;h<HID;h+=64) p += Wout[wave*HID+h]*fs[h];
    for(int off=32; off; off>>=1) p += __shfl_down(p, off);
    if(lane==0) logits[wave]=p+bout[wave];
  }
  __syncthreads();
  if(t==0){
    float mx = fmaxf(fmaxf(logits[0],logits[1]),fmaxf(logits[2],logits[3]));
    float ev[NCLASS]; float es=0.f;
    #pragma unroll
    for(int c=0;c<NCLASS;c++){ ev[c]=expf(logits[c]-mx); es+=ev[c]; }
    float loss=0.f;
    #pragma unroll
    for(int c=0;c<NCLASS;c++){
      float p=ev[c]/es;
      out[c]=p;
      float d=y[c]-p; loss+=d*d;
    }
    out[NCLASS]=loss;
  }
}

// ---------------------------------------------------------------------------
extern "C" void kernel_launch(void* const* d_in, const int* in_sizes, int n_in,
                              void* d_out, int out_size, void* d_ws, size_t ws_size,
                              hipStream_t stream){
  (void)in_sizes; (void)n_in; (void)out_size;
  const float* x_word=(const float*)d_in[0];
  const int*   x_index=(const int*)d_in[1];
  const int*   parent =(const int*)d_in[2];
  const int*   leaf   =(const int*)d_in[3];
  const float* y      =(const float*)d_in[4];
  const float* E      =(const float*)d_in[5];
  const float* W_z=(const float*)d_in[6];  const float* U_z=(const float*)d_in[7];  const float* b_z=(const float*)d_in[8];
  const float* W_r=(const float*)d_in[9];  const float* U_r=(const float*)d_in[10]; const float* b_r=(const float*)d_in[11];
  const float* W_h=(const float*)d_in[12]; const float* U_h=(const float*)d_in[13]; const float* b_h=(const float*)d_in[14];
  const float* W_out=(const float*)d_in[15]; const float* b_out=(const float*)d_in[16];

  size_t off=0;
  char* wsb=(char*)d_ws;
  auto alloc=[&](size_t b)->void*{ void* p=wsb+off; off=(off+b+255)&~(size_t)255; return p; };
  int*  meta   = (int*)  alloc(256);
  int*  lstart = (int*)  alloc((N_NODES+1)*sizeof(int));
  int*  order  = (int*)  alloc(N_NODES*sizeof(int));
  float* node_h= (float*)alloc((size_t)(N_NODES+1)*HID*sizeof(float));
  u16*  xeb    = (u16*)  alloc((size_t)N_NODES*HID*sizeof(u16));
  float* wz    = (float*)alloc((size_t)N_NODES*HID*sizeof(float));
  float* wr    = (float*)alloc((size_t)N_NODES*HID*sizeof(float));
  float* wh    = (float*)alloc((size_t)N_NODES*HID*sizeof(float));
  float* part  = (float*)alloc((size_t)LMB*HID*sizeof(float));
  u16*  Wzb    = (u16*)  alloc((size_t)HID*HID*sizeof(u16));
  u16*  Wrb    = (u16*)  alloc((size_t)HID*HID*sizeof(u16));
  u16*  Whb    = (u16*)  alloc((size_t)HID*HID*sizeof(u16));
  u16*  Uzb    = (u16*)  alloc((size_t)HID*HID*sizeof(u16));
  u16*  Urb    = (u16*)  alloc((size_t)HID*HID*sizeof(u16));
  u16*  Uhb    = (u16*)  alloc((size_t)HID*HID*sizeof(u16));
  u16*  ETb    = (u16*)(wsb+off);
  const size_t need_ET = off + (size_t)VOCAB*HID*sizeof(u16);
  const bool useET = (ws_size >= need_ET);

  k_levels<<<1,1024,0,stream>>>(parent, meta, lstart, order, node_h);
  k_prep<<<dim3(1024,6),256,0,stream>>>(W_z,W_r,W_h,U_z,U_r,U_h, Wzb,Wrb,Whb,Uzb,Urb,Uhb);
  if(useET){
    k_transpose<<<dim3((VOCAB+31)/32, HID/32),256,0,stream>>>(E, ETb);
    k_xe<<<N_NODES,256,0,stream>>>(ETb, x_word, x_index, xeb);
  }else{
    k_xe_noET<<<N_NODES,256,0,stream>>>(E, x_word, x_index, xeb);
  }
  k_gemm_in<<<dim3(HID/64, N_NODES/64, 3),256,0,stream>>>(xeb, Wzb,Wrb,Whb, b_z,b_r,b_h, wz,wr,wh);
  for(int lev=0; lev<MAXLEV; ++lev){
    k_lvlA<<<dim3(HID/32, 24, 2),256,0,stream>>>(node_h, Uzb,Urb, wz,wr, parent, lstart, order, lev);
    k_lvlC<<<dim3(HID/32, 24),256,0,stream>>>(node_h, Uhb, wz,wr,wh, parent, lstart, order, lev);
  }
  k_leafmax<<<LMB,1024,0,stream>>>(node_h, leaf, part);
  k_final2<<<1,1024,0,stream>>>(part, W_out, b_out, y, (float*)d_out);
}

// Round 19
// 619.039 us; speedup vs baseline: 12.5130x; 1.0716x over previous
//
#include <hip/hip_runtime.h>
#include <hip/hip_bf16.h>
#include <math.h>

#define N_NODES 4096
#define WPN 32
#define HID 1024
#define VOCAB 30000
#define NCLASS 4
#define NLEAVES 1024
#define MAXLEV 32
#define LMB 64
#define LPB (NLEAVES/LMB)

typedef unsigned int u32;
typedef unsigned short u16;
typedef __attribute__((ext_vector_type(8))) short short8v;
typedef __attribute__((ext_vector_type(4))) float f32x4;

__device__ __forceinline__ float sigmf(float x){ return 1.f/(1.f+expf(-x)); }
__device__ __forceinline__ u16 f2bf16(float f){
  u32 x=__float_as_uint(f);
  return (u16)((x + 0x7fffu + ((x>>16)&1u))>>16);
}
__device__ __forceinline__ float bfu(u16 v){ return __uint_as_float(((u32)v)<<16); }

// ---------------------------------------------------------------------------
// Level schedule (unchanged).
// ---------------------------------------------------------------------------
__global__ __launch_bounds__(1024) void k_levels(const int* __restrict__ parent,
                                                 int* __restrict__ meta,
                                                 int* __restrict__ lstart,
                                                 int* __restrict__ order,
                                                 float* __restrict__ node_h){
  __shared__ int dep[N_NODES];
  __shared__ int dpt[N_NODES];
  __shared__ int cnt[N_NODES];
  __shared__ int changed, maxd;
  const int t = threadIdx.x;
  for(int i=t;i<N_NODES;i+=1024){ dep[i]=parent[i]-1; dpt[i]=0; cnt[i]=0; }
  if(t==0){ maxd=0; }
  node_h[t]=0.f;
  __syncthreads();
  while(true){
    if(t==0) changed=0;
    __syncthreads();
    bool ch=false;
    for(int i=t;i<N_NODES;i+=1024){
      int d = (dep[i]<0)? 0 : (dpt[dep[i]]+1);
      if(d>dpt[i]){ dpt[i]=d; ch=true; }
    }
    if(ch) changed=1;
    __syncthreads();
    if(!changed) break;
    __syncthreads();
  }
  __syncthreads();
  for(int i=t;i<N_NODES;i+=1024){ atomicAdd(&cnt[dpt[i]],1); atomicMax(&maxd,dpt[i]); }
  __syncthreads();
  int* sc = dep;
  for(int i=t;i<N_NODES;i+=1024) sc[i]=cnt[i];
  __syncthreads();
  for(int off=1; off<N_NODES; off<<=1){
    int v[4];
    #pragma unroll
    for(int u=0;u<4;u++){ int i=t+u*1024; v[u] = (i>=off)? sc[i-off] : 0; }
    __syncthreads();
    #pragma unroll
    for(int u=0;u<4;u++){ int i=t+u*1024; sc[i]+=v[u]; }
    __syncthreads();
  }
  for(int i=t;i<N_NODES;i+=1024) lstart[i+1]=sc[i];
  if(t==0){ lstart[0]=0; meta[0]=maxd+1; }
  for(int i=t;i<N_NODES;i+=1024) cnt[i]=sc[i]-cnt[i];
  __syncthreads();
  for(int i=t;i<N_NODES;i+=1024){
    int pos = atomicAdd(&cnt[dpt[i]],1);
    order[pos]=i;
  }
}

// ---------------------------------------------------------------------------
// fp32 -> bf16 one-time: W_z,W_r,W_h,U_z,U_r,U_h. grid (1024,6).
// ---------------------------------------------------------------------------
__global__ __launch_bounds__(256) void k_prep(const float* __restrict__ Wz,
                                              const float* __restrict__ Wr,
                                              const float* __restrict__ Wh,
                                              const float* __restrict__ Uz,
                                              const float* __restrict__ Ur,
                                              const float* __restrict__ Uh,
                                              u16* __restrict__ Wzb, u16* __restrict__ Wrb,
                                              u16* __restrict__ Whb, u16* __restrict__ Uzb,
                                              u16* __restrict__ Urb, u16* __restrict__ Uhb){
  const size_t i = ((size_t)blockIdx.x*256 + threadIdx.x)*4;
  const float* srcs[6]={Wz,Wr,Wh,Uz,Ur,Uh};
  u16* dsts[6]={Wzb,Wrb,Whb,Uzb,Urb,Uhb};
  const float* src = srcs[blockIdx.y];
  u16* dst = dsts[blockIdx.y];
  const float4 v = *(const float4*)(src+i);
  ushort4 o;
  o.x=f2bf16(v.x); o.y=f2bf16(v.y); o.z=f2bf16(v.z); o.w=f2bf16(v.w);
  *(ushort4*)(dst+i) = o;
}

// ---------------------------------------------------------------------------
// E [HID][VOCAB] f32  ->  ETb [VOCAB][HID] bf16  (tiled transpose)
// ---------------------------------------------------------------------------
__global__ __launch_bounds__(256) void k_transpose(const float* __restrict__ E,
                                                   u16* __restrict__ ETb){
  __shared__ float tile[32][33];
  const int v0 = blockIdx.x*32, h0 = blockIdx.y*32;
  const int tx = threadIdx.x%32, ty = threadIdx.x/32;
  #pragma unroll
  for(int i=0;i<4;i++){
    int h = h0+ty+8*i, v = v0+tx;
    tile[ty+8*i][tx] = (v<VOCAB)? E[(size_t)h*VOCAB + v] : 0.f;
  }
  __syncthreads();
  #pragma unroll
  for(int i=0;i<4;i++){
    int v = v0+ty+8*i, h = h0+tx;
    if(v<VOCAB) ETb[(size_t)v*HID + h] = f2bf16(tile[tx][ty+8*i]);
  }
}

// ---------------------------------------------------------------------------
// xe (bf16 in/out).
// ---------------------------------------------------------------------------
__global__ __launch_bounds__(256) void k_xe(const u16* __restrict__ ETb,
                                            const float* __restrict__ xw,
                                            const int* __restrict__ xi,
                                            u16* __restrict__ xeb){
  const int n = blockIdx.x;
  __shared__ float w[WPN]; __shared__ int id[WPN];
  const int t = threadIdx.x;
  if(t<WPN){ w[t]=xw[n*WPN+t]; id[t]=xi[n*WPN+t]; }
  __syncthreads();
  const int h0 = t*4;
  float a0=0,a1=0,a2=0,a3=0;
  for(int l=0;l<WPN;l++){
    const ushort4 e = *(const ushort4*)(ETb + (size_t)id[l]*HID + h0);
    const float wl = w[l];
    a0 += wl*bfu(e.x); a1 += wl*bfu(e.y); a2 += wl*bfu(e.z); a3 += wl*bfu(e.w);
  }
  ushort4 o; o.x=f2bf16(a0); o.y=f2bf16(a1); o.z=f2bf16(a2); o.w=f2bf16(a3);
  *(ushort4*)(xeb + (size_t)n*HID + h0) = o;
}

__global__ __launch_bounds__(256) void k_xe_noET(const float* __restrict__ E,
                                                 const float* __restrict__ xw,
                                                 const int* __restrict__ xi,
                                                 u16* __restrict__ xeb){
  const int n = blockIdx.x;
  __shared__ float w[WPN]; __shared__ int id[WPN];
  const int t = threadIdx.x;
  if(t<WPN){ w[t]=xw[n*WPN+t]; id[t]=xi[n*WPN+t]; }
  __syncthreads();
  const int h0 = t*4;
  float acc[4]={0,0,0,0};
  for(int l=0;l<WPN;l++){
    const float wl=w[l]; const int ix=id[l];
    #pragma unroll
    for(int j=0;j<4;j++) acc[j] += wl*E[(size_t)(h0+j)*VOCAB + ix];
  }
  ushort4 o; o.x=f2bf16(acc[0]); o.y=f2bf16(acc[1]); o.z=f2bf16(acc[2]); o.w=f2bf16(acc[3]);
  *(ushort4*)(xeb + (size_t)n*HID + h0) = o;
}

// ---------------------------------------------------------------------------
// v19 MFMA input projections: BK=64, LDS stride 72 (conflict-free pattern
// from v18 level kernels), register prefetch, 8 MFMAs/iter.
// ---------------------------------------------------------------------------
__global__ __launch_bounds__(256) void k_gemm_in(const u16* __restrict__ xeb,
  const u16* __restrict__ W0,const u16* __restrict__ W1,const u16* __restrict__ W2,
  const float* __restrict__ b0,const float* __restrict__ b1,const float* __restrict__ b2,
  float* __restrict__ o0p,float* __restrict__ o1p,float* __restrict__ o2p){
  const int g=blockIdx.z;
  const u16* W    = (g==0)?W0:((g==1)?W1:W2);
  const float* bi = (g==0)?b0:((g==1)?b1:b2);
  float* out      = (g==0)?o0p:((g==1)?o1p:o2p);
  const int m0=blockIdx.x<<6;
  const int n0=blockIdx.y<<6;
  __shared__ __align__(16) u16 As[64*72];
  __shared__ __align__(16) u16 Bs[64*72];
  const int t=threadIdx.x, lane=t&63, w=t>>6;
  const int r1=t>>3, sc8=(t&7)<<3;          // rows r1 and r1+32, 8 elems
  const u16* ap1 = W   + (size_t)(m0+r1)*HID + sc8;
  const u16* ap2 = W   + (size_t)(m0+r1+32)*HID + sc8;
  const u16* bp1 = xeb + (size_t)(n0+r1)*HID + sc8;
  const u16* bp2 = xeb + (size_t)(n0+r1+32)*HID + sc8;
  short8v aR1=*(const short8v*)ap1, aR2=*(const short8v*)ap2;
  short8v bR1=*(const short8v*)bp1, bR2=*(const short8v*)bp2;
  const int qr=w&1, qc=w>>1;
  f32x4 acc[2][2]={};
  const int abase=(qr<<5)*72, bbase=(qc<<5)*72;
  const int lrow=(lane&15)*72, lk=((lane>>4)<<3);
  for(int k0=0;k0<HID;k0+=64){
    *(short8v*)&As[r1*72+sc8]      = aR1;
    *(short8v*)&As[(r1+32)*72+sc8] = aR2;
    *(short8v*)&Bs[r1*72+sc8]      = bR1;
    *(short8v*)&Bs[(r1+32)*72+sc8] = bR2;
    __syncthreads();
    if(k0+64<HID){
      aR1=*(const short8v*)(ap1+k0+64); aR2=*(const short8v*)(ap2+k0+64);
      bR1=*(const short8v*)(bp1+k0+64); bR2=*(const short8v*)(bp2+k0+64);
    }
    #pragma unroll
    for(int ks=0;ks<64;ks+=32){
      short8v af0 = *(const short8v*)&As[abase + lrow + ks + lk];
      short8v af1 = *(const short8v*)&As[abase + 16*72 + lrow + ks + lk];
      short8v bf0 = *(const short8v*)&Bs[bbase + lrow + ks + lk];
      short8v bf1 = *(const short8v*)&Bs[bbase + 16*72 + lrow + ks + lk];
      acc[0][0]=__builtin_amdgcn_mfma_f32_16x16x32_bf16(af0,bf0,acc[0][0],0,0,0);
      acc[0][1]=__builtin_amdgcn_mfma_f32_16x16x32_bf16(af0,bf1,acc[0][1],0,0,0);
      acc[1][0]=__builtin_amdgcn_mfma_f32_16x16x32_bf16(af1,bf0,acc[1][0],0,0,0);
      acc[1][1]=__builtin_amdgcn_mfma_f32_16x16x32_bf16(af1,bf1,acc[1][1],0,0,0);
    }
    __syncthreads();
  }
  #pragma unroll
  for(int fi=0;fi<2;fi++){
    const int o = m0 + (qr<<5) + fi*16 + ((lane>>4)<<2);
    const float4 bb = *(const float4*)(bi + o);
    #pragma unroll
    for(int fj=0;fj<2;fj++){
      const int n = n0 + (qc<<5) + fj*16 + (lane&15);
      float4 r4 = make_float4(acc[fi][fj][0]+bb.x, acc[fi][fj][1]+bb.y,
                              acc[fi][fj][2]+bb.z, acc[fi][fj][3]+bb.w);
      *(float4*)(out + (size_t)n*HID + o) = r4;
    }
  }
}

// ---------------------------------------------------------------------------
// v18 level kernels (unchanged — proven).
// ---------------------------------------------------------------------------
__global__ void k_lvlA(const float* __restrict__ node_h,
                       const u16* __restrict__ Uzb, const u16* __restrict__ Urb,
                       float* __restrict__ wz, float* __restrict__ wr,
                       const int* __restrict__ parent,
                       const int* __restrict__ lstart, const int* __restrict__ order,
                       int lev){
  const int s = lstart[lev];
  const int L = lstart[lev+1] - s;
  const int j0 = blockIdx.y<<5;
  if(j0 >= L) return;
  const int m0 = blockIdx.x<<5;
  const int gate = blockIdx.z;
  const u16* U = gate? Urb : Uzb;
  __shared__ __align__(16) u16 As[32*72];
  __shared__ __align__(16) u16 Bs[32*72];
  __shared__ int nds[32], pds[32];
  const int t=threadIdx.x, lane=t&63, w=t>>6;
  if(t<32){
    const int j=j0+t;
    const int n=(j<L)? order[s+j] : 0;
    nds[t]=n; pds[t]=(j<L)? parent[n] : 0;
  }
  __syncthreads();
  const int srow=t>>3, sc8=(t&7)<<3;
  const u16*   ap = U + (size_t)(m0+srow)*HID + sc8;
  const float* bp = node_h + (size_t)pds[srow]*HID + sc8;
  short8v aR = *(const short8v*)(ap);
  float4 bR0 = *(const float4*)(bp);
  float4 bR1 = *(const float4*)(bp+4);
  const int qr=w&1, qc=w>>1;
  f32x4 acc = {0.f,0.f,0.f,0.f};
  const int arow=(16*qr+(lane&15))*72, brow=(16*qc+(lane&15))*72;
  const int lk=((lane>>4)<<3);
  for(int k0=0;k0<HID;k0+=64){
    *(short8v*)&As[srow*72+sc8] = aR;
    ushort4 p0,p1;
    p0.x=f2bf16(bR0.x); p0.y=f2bf16(bR0.y); p0.z=f2bf16(bR0.z); p0.w=f2bf16(bR0.w);
    p1.x=f2bf16(bR1.x); p1.y=f2bf16(bR1.y); p1.z=f2bf16(bR1.z); p1.w=f2bf16(bR1.w);
    *(ushort4*)&Bs[srow*72+sc8]   = p0;
    *(ushort4*)&Bs[srow*72+sc8+4] = p1;
    __syncthreads();
    if(k0+64<HID){
      aR  = *(const short8v*)(ap + k0+64);
      bR0 = *(const float4*)(bp + k0+64);
      bR1 = *(const float4*)(bp + k0+68);
    }
    short8v af0 = *(const short8v*)&As[arow + lk];
    short8v bf0 = *(const short8v*)&Bs[brow + lk];
    acc = __builtin_amdgcn_mfma_f32_16x16x32_bf16(af0,bf0,acc,0,0,0);
    short8v af1 = *(const short8v*)&As[arow + 32 + lk];
    short8v bf1 = *(const short8v*)&Bs[brow + 32 + lk];
    acc = __builtin_amdgcn_mfma_f32_16x16x32_bf16(af1,bf1,acc,0,0,0);
    __syncthreads();
  }
  const int jl = 16*qc + (lane&15);
  if(j0 + jl < L){
    const int n = nds[jl], p = pds[jl];
    const int mb = m0 + 16*qr + ((lane>>4)<<2);
    if(gate==0){
      float4 wv = *(float4*)(wz + (size_t)n*HID + mb);
      wv.x=sigmf(wv.x+acc[0]); wv.y=sigmf(wv.y+acc[1]);
      wv.z=sigmf(wv.z+acc[2]); wv.w=sigmf(wv.w+acc[3]);
      *(float4*)(wz + (size_t)n*HID + mb) = wv;
    }else{
      float4 wv = *(float4*)(wr + (size_t)n*HID + mb);
      const float4 ph = *(const float4*)(node_h + (size_t)p*HID + mb);
      wv.x=sigmf(wv.x+acc[0])*ph.x; wv.y=sigmf(wv.y+acc[1])*ph.y;
      wv.z=sigmf(wv.z+acc[2])*ph.z; wv.w=sigmf(wv.w+acc[3])*ph.w;
      *(float4*)(wr + (size_t)n*HID + mb) = wv;
    }
  }
}

__global__ void k_lvlC(float* __restrict__ node_h,
                       const u16* __restrict__ Uhb,
                       const float* __restrict__ wz, const float* __restrict__ wr,
                       const float* __restrict__ wh,
                       const int* __restrict__ parent,
                       const int* __restrict__ lstart, const int* __restrict__ order,
                       int lev){
  const int s = lstart[lev];
  const int L = lstart[lev+1] - s;
  const int j0 = blockIdx.y<<5;
  if(j0 >= L) return;
  const int m0 = blockIdx.x<<5;
  __shared__ __align__(16) u16 As[32*72];
  __shared__ __align__(16) u16 Bs[32*72];
  __shared__ int nds[32], pds[32];
  const int t=threadIdx.x, lane=t&63, w=t>>6;
  if(t<32){
    const int j=j0+t;
    const int n=(j<L)? order[s+j] : 0;
    nds[t]=n; pds[t]=(j<L)? parent[n] : 0;
  }
  __syncthreads();
  const int srow=t>>3, sc8=(t&7)<<3;
  const u16*   ap = Uhb + (size_t)(m0+srow)*HID + sc8;
  const float* bp = wr + (size_t)nds[srow]*HID + sc8;
  short8v aR = *(const short8v*)(ap);
  float4 bR0 = *(const float4*)(bp);
  float4 bR1 = *(const float4*)(bp+4);
  const int qr=w&1, qc=w>>1;
  f32x4 acc = {0.f,0.f,0.f,0.f};
  const int arow=(16*qr+(lane&15))*72, brow=(16*qc+(lane&15))*72;
  const int lk=((lane>>4)<<3);
  for(int k0=0;k0<HID;k0+=64){
    *(short8v*)&As[srow*72+sc8] = aR;
    ushort4 p0,p1;
    p0.x=f2bf16(bR0.x); p0.y=f2bf16(bR0.y); p0.z=f2bf16(bR0.z); p0.w=f2bf16(bR0.w);
    p1.x=f2bf16(bR1.x); p1.y=f2bf16(bR1.y); p1.z=f2bf16(bR1.z); p1.w=f2bf16(bR1.w);
    *(ushort4*)&Bs[srow*72+sc8]   = p0;
    *(ushort4*)&Bs[srow*72+sc8+4] = p1;
    __syncthreads();
    if(k0+64<HID){
      aR  = *(const short8v*)(ap + k0+64);
      bR0 = *(const float4*)(bp + k0+64);
      bR1 = *(const float4*)(bp + k0+68);
    }
    short8v af0 = *(const short8v*)&As[arow + lk];
    short8v bf0 = *(const short8v*)&Bs[brow + lk];
    acc = __builtin_amdgcn_mfma_f32_16x16x32_bf16(af0,bf0,acc,0,0,0);
    short8v af1 = *(const short8v*)&As[arow + 32 + lk];
    short8v bf1 = *(const short8v*)&Bs[brow + 32 + lk];
    acc = __builtin_amdgcn_mfma_f32_16x16x32_bf16(af1,bf1,acc,0,0,0);
    __syncthreads();
  }
  const int jl = 16*qc + (lane&15);
  if(j0 + jl < L){
    const int n = nds[jl], p = pds[jl];
    const int mb = m0 + 16*qr + ((lane>>4)<<2);
    const float4 whv = *(const float4*)(wh + (size_t)n*HID + mb);
    const float4 z4  = *(const float4*)(wz + (size_t)n*HID + mb);
    const float4 ph  = *(const float4*)(node_h + (size_t)p*HID + mb);
    float4 hn;
    hn.x = z4.x*ph.x + (1.f-z4.x)*tanhf(whv.x+acc[0]);
    hn.y = z4.y*ph.y + (1.f-z4.y)*tanhf(whv.y+acc[1]);
    hn.z = z4.z*ph.z + (1.f-z4.z)*tanhf(whv.z+acc[2]);
    hn.w = z4.w*ph.w + (1.f-z4.w)*tanhf(whv.w+acc[3]);
    *(float4*)(node_h + (size_t)(n+1)*HID + mb) = hn;
  }
}

// ---------------------------------------------------------------------------
// Leaf max two-stage (unchanged).
// ---------------------------------------------------------------------------
__global__ __launch_bounds__(1024) void k_leafmax(const float* __restrict__ node_h,
                                                  const int* __restrict__ leaf,
                                                  float* __restrict__ partial){
  const int b = blockIdx.x, t = threadIdx.x;
  __shared__ int li[LPB];
  if(t<LPB) li[t] = leaf[b*LPB + t];
  __syncthreads();
  float m = -INFINITY;
  #pragma unroll
  for(int l=0;l<LPB;l++) m = fmaxf(m, node_h[(size_t)li[l]*HID + t]);
  partial[(size_t)b*HID + t] = m;
}

__global__ __launch_bounds__(1024) void k_final2(const float* __restrict__ partial,
                                                 const float* __restrict__ Wout,
                                                 const float* __restrict__ bout,
                                                 const float* __restrict__ y,
                                                 float* __restrict__ out){
  __shared__ float fs[HID];
  __shared__ float logits[NCLASS];
  const int t=threadIdx.x;
  float m=-INFINITY;
  for(int b=0;b<LMB;b++) m = fmaxf(m, partial[(size_t)b*HID + t]);
  fs[t]=m;
  __syncthreads();
  const int wave=t>>6, lane=t&63;
  if(wave<NCLASS){
    float p=0.f;
    for(int h=lane;h<HID;h+=64) p += Wout[wave*HID+h]*fs[h];
    for(int off=32; off; off>>=1) p += __shfl_down(p, off);
    if(lane==0) logits[wave]=p+bout[wave];
  }
  __syncthreads();
  if(t==0){
    float mx = fmaxf(fmaxf(logits[0],logits[1]),fmaxf(logits[2],logits[3]));
    float ev[NCLASS]; float es=0.f;
    #pragma unroll
    for(int c=0;c<NCLASS;c++){ ev[c]=expf(logits[c]-mx); es+=ev[c]; }
    float loss=0.f;
    #pragma unroll
    for(int c=0;c<NCLASS;c++){
      float p=ev[c]/es;
      out[c]=p;
      float d=y[c]-p; loss+=d*d;
    }
    out[NCLASS]=loss;
  }
}

// ---------------------------------------------------------------------------
extern "C" void kernel_launch(void* const* d_in, const int* in_sizes, int n_in,
                              void* d_out, int out_size, void* d_ws, size_t ws_size,
                              hipStream_t stream){
  (void)in_sizes; (void)n_in; (void)out_size;
  const float* x_word=(const float*)d_in[0];
  const int*   x_index=(const int*)d_in[1];
  const int*   parent =(const int*)d_in[2];
  const int*   leaf   =(const int*)d_in[3];
  const float* y      =(const float*)d_in[4];
  const float* E      =(const float*)d_in[5];
  const float* W_z=(const float*)d_in[6];  const float* U_z=(const float*)d_in[7];  const float* b_z=(const float*)d_in[8];
  const float* W_r=(const float*)d_in[9];  const float* U_r=(const float*)d_in[10]; const float* b_r=(const float*)d_in[11];
  const float* W_h=(const float*)d_in[12]; const float* U_h=(const float*)d_in[13]; const float* b_h=(const float*)d_in[14];
  const float* W_out=(const float*)d_in[15]; const float* b_out=(const float*)d_in[16];

  size_t off=0;
  char* wsb=(char*)d_ws;
  auto alloc=[&](size_t b)->void*{ void* p=wsb+off; off=(off+b+255)&~(size_t)255; return p; };
  int*  meta   = (int*)  alloc(256);
  int*  lstart = (int*)  alloc((N_NODES+1)*sizeof(int));
  int*  order  = (int*)  alloc(N_NODES*sizeof(int));
  float* node_h= (float*)alloc((size_t)(N_NODES+1)*HID*sizeof(float));
  u16*  xeb    = (u16*)  alloc((size_t)N_NODES*HID*sizeof(u16));
  float* wz    = (float*)alloc((size_t)N_NODES*HID*sizeof(float));
  float* wr    = (float*)alloc((size_t)N_NODES*HID*sizeof(float));
  float* wh    = (float*)alloc((size_t)N_NODES*HID*sizeof(float));
  float* part  = (float*)alloc((size_t)LMB*HID*sizeof(float));
  u16*  Wzb    = (u16*)  alloc((size_t)HID*HID*sizeof(u16));
  u16*  Wrb    = (u16*)  alloc((size_t)HID*HID*sizeof(u16));
  u16*  Whb    = (u16*)  alloc((size_t)HID*HID*sizeof(u16));
  u16*  Uzb    = (u16*)  alloc((size_t)HID*HID*sizeof(u16));
  u16*  Urb    = (u16*)  alloc((size_t)HID*HID*sizeof(u16));
  u16*  Uhb    = (u16*)  alloc((size_t)HID*HID*sizeof(u16));
  u16*  ETb    = (u16*)(wsb+off);
  const size_t need_ET = off + (size_t)VOCAB*HID*sizeof(u16);
  const bool useET = (ws_size >= need_ET);

  k_levels<<<1,1024,0,stream>>>(parent, meta, lstart, order, node_h);
  k_prep<<<dim3(1024,6),256,0,stream>>>(W_z,W_r,W_h,U_z,U_r,U_h, Wzb,Wrb,Whb,Uzb,Urb,Uhb);
  if(useET){
    k_transpose<<<dim3((VOCAB+31)/32, HID/32),256,0,stream>>>(E, ETb);
    k_xe<<<N_NODES,256,0,stream>>>(ETb, x_word, x_index, xeb);
  }else{
    k_xe_noET<<<N_NODES,256,0,stream>>>(E, x_word, x_index, xeb);
  }
  k_gemm_in<<<dim3(HID/64, N_NODES/64, 3),256,0,stream>>>(xeb, Wzb,Wrb,Whb, b_z,b_r,b_h, wz,wr,wh);
  for(int lev=0; lev<MAXLEV; ++lev){
    k_lvlA<<<dim3(HID/32, 24, 2),256,0,stream>>>(node_h, Uzb,Urb, wz,wr, parent, lstart, order, lev);
    k_lvlC<<<dim3(HID/32, 24),256,0,stream>>>(node_h, Uhb, wz,wr,wh, parent, lstart, order, lev);
  }
  k_leafmax<<<LMB,1024,0,stream>>>(node_h, leaf, part);
  k_final2<<<1,1024,0,stream>>>(part, W_out, b_out, y, (float*)d_out);
}

// Round 20
// 601.598 us; speedup vs baseline: 12.8757x; 1.0290x over previous
//
#include <hip/hip_runtime.h>
#include <hip/hip_bf16.h>
#include <math.h>

#define N_NODES 4096
#define WPN 32
#define HID 1024
#define VOCAB 30000
#define NCLASS 4
#define NLEAVES 1024
#define MAXLEV 28
#define LMB 64
#define LPB (NLEAVES/LMB)

typedef unsigned int u32;
typedef unsigned short u16;
typedef __attribute__((ext_vector_type(8))) short short8v;
typedef __attribute__((ext_vector_type(4))) float f32x4;

__device__ __forceinline__ float sigmf(float x){ return 1.f/(1.f+expf(-x)); }
__device__ __forceinline__ u16 f2bf16(float f){
  u32 x=__float_as_uint(f);
  return (u16)((x + 0x7fffu + ((x>>16)&1u))>>16);
}
__device__ __forceinline__ float bfu(u16 v){ return __uint_as_float(((u32)v)<<16); }

// ---------------------------------------------------------------------------
// Level schedule (unchanged).
// ---------------------------------------------------------------------------
__global__ __launch_bounds__(1024) void k_levels(const int* __restrict__ parent,
                                                 int* __restrict__ meta,
                                                 int* __restrict__ lstart,
                                                 int* __restrict__ order,
                                                 float* __restrict__ node_h){
  __shared__ int dep[N_NODES];
  __shared__ int dpt[N_NODES];
  __shared__ int cnt[N_NODES];
  __shared__ int changed, maxd;
  const int t = threadIdx.x;
  for(int i=t;i<N_NODES;i+=1024){ dep[i]=parent[i]-1; dpt[i]=0; cnt[i]=0; }
  if(t==0){ maxd=0; }
  node_h[t]=0.f;
  __syncthreads();
  while(true){
    if(t==0) changed=0;
    __syncthreads();
    bool ch=false;
    for(int i=t;i<N_NODES;i+=1024){
      int d = (dep[i]<0)? 0 : (dpt[dep[i]]+1);
      if(d>dpt[i]){ dpt[i]=d; ch=true; }
    }
    if(ch) changed=1;
    __syncthreads();
    if(!changed) break;
    __syncthreads();
  }
  __syncthreads();
  for(int i=t;i<N_NODES;i+=1024){ atomicAdd(&cnt[dpt[i]],1); atomicMax(&maxd,dpt[i]); }
  __syncthreads();
  int* sc = dep;
  for(int i=t;i<N_NODES;i+=1024) sc[i]=cnt[i];
  __syncthreads();
  for(int off=1; off<N_NODES; off<<=1){
    int v[4];
    #pragma unroll
    for(int u=0;u<4;u++){ int i=t+u*1024; v[u] = (i>=off)? sc[i-off] : 0; }
    __syncthreads();
    #pragma unroll
    for(int u=0;u<4;u++){ int i=t+u*1024; sc[i]+=v[u]; }
    __syncthreads();
  }
  for(int i=t;i<N_NODES;i+=1024) lstart[i+1]=sc[i];
  if(t==0){ lstart[0]=0; meta[0]=maxd+1; }
  for(int i=t;i<N_NODES;i+=1024) cnt[i]=sc[i]-cnt[i];
  __syncthreads();
  for(int i=t;i<N_NODES;i+=1024){
    int pos = atomicAdd(&cnt[dpt[i]],1);
    order[pos]=i;
  }
}

// ---------------------------------------------------------------------------
// fp32 -> bf16 one-time conversions.
// ---------------------------------------------------------------------------
__global__ __launch_bounds__(256) void k_prep(const float* __restrict__ Wz,
                                              const float* __restrict__ Wr,
                                              const float* __restrict__ Wh,
                                              const float* __restrict__ Uz,
                                              const float* __restrict__ Ur,
                                              const float* __restrict__ Uh,
                                              u16* __restrict__ Wzb, u16* __restrict__ Wrb,
                                              u16* __restrict__ Whb, u16* __restrict__ Uzb,
                                              u16* __restrict__ Urb, u16* __restrict__ Uhb){
  const size_t i = ((size_t)blockIdx.x*256 + threadIdx.x)*4;
  const float* srcs[6]={Wz,Wr,Wh,Uz,Ur,Uh};
  u16* dsts[6]={Wzb,Wrb,Whb,Uzb,Urb,Uhb};
  const float* src = srcs[blockIdx.y];
  u16* dst = dsts[blockIdx.y];
  const float4 v = *(const float4*)(src+i);
  ushort4 o;
  o.x=f2bf16(v.x); o.y=f2bf16(v.y); o.z=f2bf16(v.z); o.w=f2bf16(v.w);
  *(ushort4*)(dst+i) = o;
}

// ---------------------------------------------------------------------------
// E [HID][VOCAB] f32  ->  ETb [VOCAB][HID] bf16
// ---------------------------------------------------------------------------
__global__ __launch_bounds__(256) void k_transpose(const float* __restrict__ E,
                                                   u16* __restrict__ ETb){
  __shared__ float tile[32][33];
  const int v0 = blockIdx.x*32, h0 = blockIdx.y*32;
  const int tx = threadIdx.x%32, ty = threadIdx.x/32;
  #pragma unroll
  for(int i=0;i<4;i++){
    int h = h0+ty+8*i, v = v0+tx;
    tile[ty+8*i][tx] = (v<VOCAB)? E[(size_t)h*VOCAB + v] : 0.f;
  }
  __syncthreads();
  #pragma unroll
  for(int i=0;i<4;i++){
    int v = v0+ty+8*i, h = h0+tx;
    if(v<VOCAB) ETb[(size_t)v*HID + h] = f2bf16(tile[tx][ty+8*i]);
  }
}

// ---------------------------------------------------------------------------
// xe (bf16 in/out).
// ---------------------------------------------------------------------------
__global__ __launch_bounds__(256) void k_xe(const u16* __restrict__ ETb,
                                            const float* __restrict__ xw,
                                            const int* __restrict__ xi,
                                            u16* __restrict__ xeb){
  const int n = blockIdx.x;
  __shared__ float w[WPN]; __shared__ int id[WPN];
  const int t = threadIdx.x;
  if(t<WPN){ w[t]=xw[n*WPN+t]; id[t]=xi[n*WPN+t]; }
  __syncthreads();
  const int h0 = t*4;
  float a0=0,a1=0,a2=0,a3=0;
  for(int l=0;l<WPN;l++){
    const ushort4 e = *(const ushort4*)(ETb + (size_t)id[l]*HID + h0);
    const float wl = w[l];
    a0 += wl*bfu(e.x); a1 += wl*bfu(e.y); a2 += wl*bfu(e.z); a3 += wl*bfu(e.w);
  }
  ushort4 o; o.x=f2bf16(a0); o.y=f2bf16(a1); o.z=f2bf16(a2); o.w=f2bf16(a3);
  *(ushort4*)(xeb + (size_t)n*HID + h0) = o;
}

__global__ __launch_bounds__(256) void k_xe_noET(const float* __restrict__ E,
                                                 const float* __restrict__ xw,
                                                 const int* __restrict__ xi,
                                                 u16* __restrict__ xeb){
  const int n = blockIdx.x;
  __shared__ float w[WPN]; __shared__ int id[WPN];
  const int t = threadIdx.x;
  if(t<WPN){ w[t]=xw[n*WPN+t]; id[t]=xi[n*WPN+t]; }
  __syncthreads();
  const int h0 = t*4;
  float acc[4]={0,0,0,0};
  for(int l=0;l<WPN;l++){
    const float wl=w[l]; const int ix=id[l];
    #pragma unroll
    for(int j=0;j<4;j++) acc[j] += wl*E[(size_t)(h0+j)*VOCAB + ix];
  }
  ushort4 o; o.x=f2bf16(acc[0]); o.y=f2bf16(acc[1]); o.z=f2bf16(acc[2]); o.w=f2bf16(acc[3]);
  *(ushort4*)(xeb + (size_t)n*HID + h0) = o;
}

// ---------------------------------------------------------------------------
// MFMA input projections (v19, unchanged — ~40us).
// ---------------------------------------------------------------------------
__global__ __launch_bounds__(256) void k_gemm_in(const u16* __restrict__ xeb,
  const u16* __restrict__ W0,const u16* __restrict__ W1,const u16* __restrict__ W2,
  const float* __restrict__ b0,const float* __restrict__ b1,const float* __restrict__ b2,
  float* __restrict__ o0p,float* __restrict__ o1p,float* __restrict__ o2p){
  const int g=blockIdx.z;
  const u16* W    = (g==0)?W0:((g==1)?W1:W2);
  const float* bi = (g==0)?b0:((g==1)?b1:b2);
  float* out      = (g==0)?o0p:((g==1)?o1p:o2p);
  const int m0=blockIdx.x<<6;
  const int n0=blockIdx.y<<6;
  __shared__ __align__(16) u16 As[64*72];
  __shared__ __align__(16) u16 Bs[64*72];
  const int t=threadIdx.x, lane=t&63, w=t>>6;
  const int r1=t>>3, sc8=(t&7)<<3;
  const u16* ap1 = W   + (size_t)(m0+r1)*HID + sc8;
  const u16* ap2 = W   + (size_t)(m0+r1+32)*HID + sc8;
  const u16* bp1 = xeb + (size_t)(n0+r1)*HID + sc8;
  const u16* bp2 = xeb + (size_t)(n0+r1+32)*HID + sc8;
  short8v aR1=*(const short8v*)ap1, aR2=*(const short8v*)ap2;
  short8v bR1=*(const short8v*)bp1, bR2=*(const short8v*)bp2;
  const int qr=w&1, qc=w>>1;
  f32x4 acc[2][2]={};
  const int abase=(qr<<5)*72, bbase=(qc<<5)*72;
  const int lrow=(lane&15)*72, lk=((lane>>4)<<3);
  for(int k0=0;k0<HID;k0+=64){
    *(short8v*)&As[r1*72+sc8]      = aR1;
    *(short8v*)&As[(r1+32)*72+sc8] = aR2;
    *(short8v*)&Bs[r1*72+sc8]      = bR1;
    *(short8v*)&Bs[(r1+32)*72+sc8] = bR2;
    __syncthreads();
    if(k0+64<HID){
      aR1=*(const short8v*)(ap1+k0+64); aR2=*(const short8v*)(ap2+k0+64);
      bR1=*(const short8v*)(bp1+k0+64); bR2=*(const short8v*)(bp2+k0+64);
    }
    #pragma unroll
    for(int ks=0;ks<64;ks+=32){
      short8v af0 = *(const short8v*)&As[abase + lrow + ks + lk];
      short8v af1 = *(const short8v*)&As[abase + 16*72 + lrow + ks + lk];
      short8v bf0 = *(const short8v*)&Bs[bbase + lrow + ks + lk];
      short8v bf1 = *(const short8v*)&Bs[bbase + 16*72 + lrow + ks + lk];
      acc[0][0]=__builtin_amdgcn_mfma_f32_16x16x32_bf16(af0,bf0,acc[0][0],0,0,0);
      acc[0][1]=__builtin_amdgcn_mfma_f32_16x16x32_bf16(af0,bf1,acc[0][1],0,0,0);
      acc[1][0]=__builtin_amdgcn_mfma_f32_16x16x32_bf16(af1,bf0,acc[1][0],0,0,0);
      acc[1][1]=__builtin_amdgcn_mfma_f32_16x16x32_bf16(af1,bf1,acc[1][1],0,0,0);
    }
    __syncthreads();
  }
  #pragma unroll
  for(int fi=0;fi<2;fi++){
    const int o = m0 + (qr<<5) + fi*16 + ((lane>>4)<<2);
    const float4 bb = *(const float4*)(bi + o);
    #pragma unroll
    for(int fj=0;fj<2;fj++){
      const int n = n0 + (qc<<5) + fj*16 + (lane&15);
      float4 r4 = make_float4(acc[fi][fj][0]+bb.x, acc[fi][fj][1]+bb.y,
                              acc[fi][fj][2]+bb.z, acc[fi][fj][3]+bb.w);
      *(float4*)(out + (size_t)n*HID + o) = r4;
    }
  }
}

// ---------------------------------------------------------------------------
// v20 level kernels: BK=128 (8 k-iters, 4 MFMA/iter), LDS stride 136
// (same 4r-mod-32 bank pattern as proven stride 72), register prefetch.
// ---------------------------------------------------------------------------
__global__ void k_lvlA(const float* __restrict__ node_h,
                       const u16* __restrict__ Uzb, const u16* __restrict__ Urb,
                       float* __restrict__ wz, float* __restrict__ wr,
                       const int* __restrict__ parent,
                       const int* __restrict__ lstart, const int* __restrict__ order,
                       int lev){
  const int s = lstart[lev];
  const int L = lstart[lev+1] - s;
  const int j0 = blockIdx.y<<5;
  if(j0 >= L) return;
  const int m0 = blockIdx.x<<5;
  const int gate = blockIdx.z;
  const u16* U = gate? Urb : Uzb;
  __shared__ __align__(16) u16 As[32*136];
  __shared__ __align__(16) u16 Bs[32*136];
  __shared__ int nds[32], pds[32];
  const int t=threadIdx.x, lane=t&63, w=t>>6;
  if(t<32){
    const int j=j0+t;
    const int n=(j<L)? order[s+j] : 0;
    nds[t]=n; pds[t]=(j<L)? parent[n] : 0;
  }
  __syncthreads();
  const int srow=t>>3, sc16=(t&7)<<4;          // row 0..31, 16 elems of 128-k chunk
  const u16*   ap = U + (size_t)(m0+srow)*HID + sc16;
  const float* bp = node_h + (size_t)pds[srow]*HID + sc16;
  short8v aR0=*(const short8v*)ap, aR1=*(const short8v*)(ap+8);
  float4 bR0=*(const float4*)bp,   bR1=*(const float4*)(bp+4);
  float4 bR2=*(const float4*)(bp+8), bR3=*(const float4*)(bp+12);
  const int qr=w&1, qc=w>>1;
  f32x4 acc = {0.f,0.f,0.f,0.f};
  const int arow=(16*qr+(lane&15))*136, brow=(16*qc+(lane&15))*136;
  const int lk=((lane>>4)<<3);
  for(int k0=0;k0<HID;k0+=128){
    *(short8v*)&As[srow*136+sc16]   = aR0;
    *(short8v*)&As[srow*136+sc16+8] = aR1;
    ushort4 p0,p1,p2,p3;
    p0.x=f2bf16(bR0.x); p0.y=f2bf16(bR0.y); p0.z=f2bf16(bR0.z); p0.w=f2bf16(bR0.w);
    p1.x=f2bf16(bR1.x); p1.y=f2bf16(bR1.y); p1.z=f2bf16(bR1.z); p1.w=f2bf16(bR1.w);
    p2.x=f2bf16(bR2.x); p2.y=f2bf16(bR2.y); p2.z=f2bf16(bR2.z); p2.w=f2bf16(bR2.w);
    p3.x=f2bf16(bR3.x); p3.y=f2bf16(bR3.y); p3.z=f2bf16(bR3.z); p3.w=f2bf16(bR3.w);
    *(ushort4*)&Bs[srow*136+sc16]    = p0;
    *(ushort4*)&Bs[srow*136+sc16+4]  = p1;
    *(ushort4*)&Bs[srow*136+sc16+8]  = p2;
    *(ushort4*)&Bs[srow*136+sc16+12] = p3;
    __syncthreads();
    if(k0+128<HID){
      aR0=*(const short8v*)(ap+k0+128); aR1=*(const short8v*)(ap+k0+136);
      bR0=*(const float4*)(bp+k0+128);  bR1=*(const float4*)(bp+k0+132);
      bR2=*(const float4*)(bp+k0+136);  bR3=*(const float4*)(bp+k0+140);
    }
    #pragma unroll
    for(int ks=0;ks<128;ks+=32){
      short8v af = *(const short8v*)&As[arow + ks + lk];
      short8v bf = *(const short8v*)&Bs[brow + ks + lk];
      acc = __builtin_amdgcn_mfma_f32_16x16x32_bf16(af,bf,acc,0,0,0);
    }
    __syncthreads();
  }
  const int jl = 16*qc + (lane&15);
  if(j0 + jl < L){
    const int n = nds[jl], p = pds[jl];
    const int mb = m0 + 16*qr + ((lane>>4)<<2);
    if(gate==0){
      float4 wv = *(float4*)(wz + (size_t)n*HID + mb);
      wv.x=sigmf(wv.x+acc[0]); wv.y=sigmf(wv.y+acc[1]);
      wv.z=sigmf(wv.z+acc[2]); wv.w=sigmf(wv.w+acc[3]);
      *(float4*)(wz + (size_t)n*HID + mb) = wv;
    }else{
      float4 wv = *(float4*)(wr + (size_t)n*HID + mb);
      const float4 ph = *(const float4*)(node_h + (size_t)p*HID + mb);
      wv.x=sigmf(wv.x+acc[0])*ph.x; wv.y=sigmf(wv.y+acc[1])*ph.y;
      wv.z=sigmf(wv.z+acc[2])*ph.z; wv.w=sigmf(wv.w+acc[3])*ph.w;
      *(float4*)(wr + (size_t)n*HID + mb) = wv;
    }
  }
}

__global__ void k_lvlC(float* __restrict__ node_h,
                       const u16* __restrict__ Uhb,
                       const float* __restrict__ wz, const float* __restrict__ wr,
                       const float* __restrict__ wh,
                       const int* __restrict__ parent,
                       const int* __restrict__ lstart, const int* __restrict__ order,
                       int lev){
  const int s = lstart[lev];
  const int L = lstart[lev+1] - s;
  const int j0 = blockIdx.y<<5;
  if(j0 >= L) return;
  const int m0 = blockIdx.x<<5;
  __shared__ __align__(16) u16 As[32*136];
  __shared__ __align__(16) u16 Bs[32*136];
  __shared__ int nds[32], pds[32];
  const int t=threadIdx.x, lane=t&63, w=t>>6;
  if(t<32){
    const int j=j0+t;
    const int n=(j<L)? order[s+j] : 0;
    nds[t]=n; pds[t]=(j<L)? parent[n] : 0;
  }
  __syncthreads();
  const int srow=t>>3, sc16=(t&7)<<4;
  const u16*   ap = Uhb + (size_t)(m0+srow)*HID + sc16;
  const float* bp = wr + (size_t)nds[srow]*HID + sc16;
  short8v aR0=*(const short8v*)ap, aR1=*(const short8v*)(ap+8);
  float4 bR0=*(const float4*)bp,   bR1=*(const float4*)(bp+4);
  float4 bR2=*(const float4*)(bp+8), bR3=*(const float4*)(bp+12);
  const int qr=w&1, qc=w>>1;
  f32x4 acc = {0.f,0.f,0.f,0.f};
  const int arow=(16*qr+(lane&15))*136, brow=(16*qc+(lane&15))*136;
  const int lk=((lane>>4)<<3);
  for(int k0=0;k0<HID;k0+=128){
    *(short8v*)&As[srow*136+sc16]   = aR0;
    *(short8v*)&As[srow*136+sc16+8] = aR1;
    ushort4 p0,p1,p2,p3;
    p0.x=f2bf16(bR0.x); p0.y=f2bf16(bR0.y); p0.z=f2bf16(bR0.z); p0.w=f2bf16(bR0.w);
    p1.x=f2bf16(bR1.x); p1.y=f2bf16(bR1.y); p1.z=f2bf16(bR1.z); p1.w=f2bf16(bR1.w);
    p2.x=f2bf16(bR2.x); p2.y=f2bf16(bR2.y); p2.z=f2bf16(bR2.z); p2.w=f2bf16(bR2.w);
    p3.x=f2bf16(bR3.x); p3.y=f2bf16(bR3.y); p3.z=f2bf16(bR3.z); p3.w=f2bf16(bR3.w);
    *(ushort4*)&Bs[srow*136+sc16]    = p0;
    *(ushort4*)&Bs[srow*136+sc16+4]  = p1;
    *(ushort4*)&Bs[srow*136+sc16+8]  = p2;
    *(ushort4*)&Bs[srow*136+sc16+12] = p3;
    __syncthreads();
    if(k0+128<HID){
      aR0=*(const short8v*)(ap+k0+128); aR1=*(const short8v*)(ap+k0+136);
      bR0=*(const float4*)(bp+k0+128);  bR1=*(const float4*)(bp+k0+132);
      bR2=*(const float4*)(bp+k0+136);  bR3=*(const float4*)(bp+k0+140);
    }
    #pragma unroll
    for(int ks=0;ks<128;ks+=32){
      short8v af = *(const short8v*)&As[arow + ks + lk];
      short8v bf = *(const short8v*)&Bs[brow + ks + lk];
      acc = __builtin_amdgcn_mfma_f32_16x16x32_bf16(af,bf,acc,0,0,0);
    }
    __syncthreads();
  }
  const int jl = 16*qc + (lane&15);
  if(j0 + jl < L){
    const int n = nds[jl], p = pds[jl];
    const int mb = m0 + 16*qr + ((lane>>4)<<2);
    const float4 whv = *(const float4*)(wh + (size_t)n*HID + mb);
    const float4 z4  = *(const float4*)(wz + (size_t)n*HID + mb);
    const float4 ph  = *(const float4*)(node_h + (size_t)p*HID + mb);
    float4 hn;
    hn.x = z4.x*ph.x + (1.f-z4.x)*tanhf(whv.x+acc[0]);
    hn.y = z4.y*ph.y + (1.f-z4.y)*tanhf(whv.y+acc[1]);
    hn.z = z4.z*ph.z + (1.f-z4.z)*tanhf(whv.z+acc[2]);
    hn.w = z4.w*ph.w + (1.f-z4.w)*tanhf(whv.w+acc[3]);
    *(float4*)(node_h + (size_t)(n+1)*HID + mb) = hn;
  }
}

// ---------------------------------------------------------------------------
// Leaf max two-stage (unchanged).
// ---------------------------------------------------------------------------
__global__ __launch_bounds__(1024) void k_leafmax(const float* __restrict__ node_h,
                                                  const int* __restrict__ leaf,
                                                  float* __restrict__ partial){
  const int b = blockIdx.x, t = threadIdx.x;
  __shared__ int li[LPB];
  if(t<LPB) li[t] = leaf[b*LPB + t];
  __syncthreads();
  float m = -INFINITY;
  #pragma unroll
  for(int l=0;l<LPB;l++) m = fmaxf(m, node_h[(size_t)li[l]*HID + t]);
  partial[(size_t)b*HID + t] = m;
}

__global__ __launch_bounds__(1024) void k_final2(const float* __restrict__ partial,
                                                 const float* __restrict__ Wout,
                                                 const float* __restrict__ bout,
                                                 const float* __restrict__ y,
                                                 float* __restrict__ out){
  __shared__ float fs[HID];
  __shared__ float logits[NCLASS];
  const int t=threadIdx.x;
  float m=-INFINITY;
  for(int b=0;b<LMB;b++) m = fmaxf(m, partial[(size_t)b*HID + t]);
  fs[t]=m;
  __syncthreads();
  const int wave=t>>6, lane=t&63;
  if(wave<NCLASS){
    float p=0.f;
    for(int h=lane;h<HID;h+=64) p += Wout[wave*HID+h]*fs[h];
    for(int off=32; off; off>>=1) p += __shfl_down(p, off);
    if(lane==0) logits[wave]=p+bout[wave];
  }
  __syncthreads();
  if(t==0){
    float mx = fmaxf(fmaxf(logits[0],logits[1]),fmaxf(logits[2],logits[3]));
    float ev[NCLASS]; float es=0.f;
    #pragma unroll
    for(int c=0;c<NCLASS;c++){ ev[c]=expf(logits[c]-mx); es+=ev[c]; }
    float loss=0.f;
    #pragma unroll
    for(int c=0;c<NCLASS;c++){
      float p=ev[c]/es;
      out[c]=p;
      float d=y[c]-p; loss+=d*d;
    }
    out[NCLASS]=loss;
  }
}

// ---------------------------------------------------------------------------
extern "C" void kernel_launch(void* const* d_in, const int* in_sizes, int n_in,
                              void* d_out, int out_size, void* d_ws, size_t ws_size,
                              hipStream_t stream){
  (void)in_sizes; (void)n_in; (void)out_size;
  const float* x_word=(const float*)d_in[0];
  const int*   x_index=(const int*)d_in[1];
  const int*   parent =(const int*)d_in[2];
  const int*   leaf   =(const int*)d_in[3];
  const float* y      =(const float*)d_in[4];
  const float* E      =(const float*)d_in[5];
  const float* W_z=(const float*)d_in[6];  const float* U_z=(const float*)d_in[7];  const float* b_z=(const float*)d_in[8];
  const float* W_r=(const float*)d_in[9];  const float* U_r=(const float*)d_in[10]; const float* b_r=(const float*)d_in[11];
  const float* W_h=(const float*)d_in[12]; const float* U_h=(const float*)d_in[13]; const float* b_h=(const float*)d_in[14];
  const float* W_out=(const float*)d_in[15]; const float* b_out=(const float*)d_in[16];

  size_t off=0;
  char* wsb=(char*)d_ws;
  auto alloc=[&](size_t b)->void*{ void* p=wsb+off; off=(off+b+255)&~(size_t)255; return p; };
  int*  meta   = (int*)  alloc(256);
  int*  lstart = (int*)  alloc((N_NODES+1)*sizeof(int));
  int*  order  = (int*)  alloc(N_NODES*sizeof(int));
  float* node_h= (float*)alloc((size_t)(N_NODES+1)*HID*sizeof(float));
  u16*  xeb    = (u16*)  alloc((size_t)N_NODES*HID*sizeof(u16));
  float* wz    = (float*)alloc((size_t)N_NODES*HID*sizeof(float));
  float* wr    = (float*)alloc((size_t)N_NODES*HID*sizeof(float));
  float* wh    = (float*)alloc((size_t)N_NODES*HID*sizeof(float));
  float* part  = (float*)alloc((size_t)LMB*HID*sizeof(float));
  u16*  Wzb    = (u16*)  alloc((size_t)HID*HID*sizeof(u16));
  u16*  Wrb    = (u16*)  alloc((size_t)HID*HID*sizeof(u16));
  u16*  Whb    = (u16*)  alloc((size_t)HID*HID*sizeof(u16));
  u16*  Uzb    = (u16*)  alloc((size_t)HID*HID*sizeof(u16));
  u16*  Urb    = (u16*)  alloc((size_t)HID*HID*sizeof(u16));
  u16*  Uhb    = (u16*)  alloc((size_t)HID*HID*sizeof(u16));
  u16*  ETb    = (u16*)(wsb+off);
  const size_t need_ET = off + (size_t)VOCAB*HID*sizeof(u16);
  const bool useET = (ws_size >= need_ET);

  k_levels<<<1,1024,0,stream>>>(parent, meta, lstart, order, node_h);
  k_prep<<<dim3(1024,6),256,0,stream>>>(W_z,W_r,W_h,U_z,U_r,U_h, Wzb,Wrb,Whb,Uzb,Urb,Uhb);
  if(useET){
    k_transpose<<<dim3((VOCAB+31)/32, HID/32),256,0,stream>>>(E, ETb);
    k_xe<<<N_NODES,256,0,stream>>>(ETb, x_word, x_index, xeb);
  }else{
    k_xe_noET<<<N_NODES,256,0,stream>>>(E, x_word, x_index, xeb);
  }
  k_gemm_in<<<dim3(HID/64, N_NODES/64, 3),256,0,stream>>>(xeb, Wzb,Wrb,Whb, b_z,b_r,b_h, wz,wr,wh);
  for(int lev=0; lev<MAXLEV; ++lev){
    k_lvlA<<<dim3(HID/32, 24, 2),256,0,stream>>>(node_h, Uzb,Urb, wz,wr, parent, lstart, order, lev);
    k_lvlC<<<dim3(HID/32, 24),256,0,stream>>>(node_h, Uhb, wz,wr,wh, parent, lstart, order, lev);
  }
  k_leafmax<<<LMB,1024,0,stream>>>(node_h, leaf, part);
  k_final2<<<1,1024,0,stream>>>(part, W_out, b_out, y, (float*)d_out);
}